// Round 26
// baseline (1506.024 us; speedup 1.0000x reference)
//
#include <hip/hip_runtime.h>
#include <hip/hip_bf16.h>
#include <math.h>

#define B_ 2
#define S_ 1024
#define D_ 1024
#define H_ 16
#define HD_ 64
#define L_ 8
#define DFF_ 4096
#define V_ 32000
#define M_ (B_*S_)   /* 2048 rows */

typedef unsigned short ushort_t;
typedef __attribute__((ext_vector_type(8))) __bf16 bf16x8_t;
typedef __attribute__((ext_vector_type(4))) float f32x4_t;

__device__ __forceinline__ ushort_t f2bf(float f) {
    union { float f; unsigned u; } x; x.f = f;
    unsigned r = x.u + 0x7fffu + ((x.u >> 16) & 1u);
    return (ushort_t)(r >> 16);
}
__device__ __forceinline__ float bf2f(ushort_t u) {
    union { unsigned u; float f; } x; x.u = ((unsigned)u) << 16; return x.f;
}

__device__ __forceinline__ void gload_lds16(const void* g, void* l) {
    __builtin_amdgcn_global_load_lds(
        (const __attribute__((address_space(1))) void*)g,
        (__attribute__((address_space(3))) void*)l, 16, 0, 0);
}

// ---------------------------------------------------------------- embedding
__global__ __launch_bounds__(256) void embed_k(const int* __restrict__ x,
                                               const float* __restrict__ emb,
                                               float* __restrict__ h) {
    int row = blockIdx.x;
    int tok = x[row];
    const float4* src = (const float4*)(emb + (size_t)tok * D_);
    float4* dst = (float4*)(h + (size_t)row * D_);
    dst[threadIdx.x] = src[threadIdx.x];
}

// ---------------------------------------------- residual + split-K reduce
// h += p0 + p1 (fp32). Only used for the last-layer W2 partials (the final
// ln_wt writes wdecT over pbuf's region, so fusing there would race).
__global__ __launch_bounds__(256) void resadd_k(float* __restrict__ h,
                                                const float* __restrict__ p0,
                                                const float* __restrict__ p1) {
    size_t i = (size_t)blockIdx.x * 256 + threadIdx.x;
    float4 a = ((const float4*)h)[i];
    float4 b = ((const float4*)p0)[i];
    float4 c = ((const float4*)p1)[i];
    a.x += b.x + c.x; a.y += b.y + c.y; a.z += b.z + c.z; a.w += b.w + c.w;
    ((float4*)h)[i] = a;
}

// ------------------------------------------------------------ device bodies
// LN (faithful: divide by var + 1e-12, NO sqrt). Optional fused split-K
// reduce: h[row] += p0+p1 (+p2+p3) first (row-exclusive, fp32).
__device__ __forceinline__ void ln_body(int row, float* __restrict__ x,
                                        const float* __restrict__ p0,
                                        const float* __restrict__ p1,
                                        const float* __restrict__ p2,
                                        const float* __restrict__ p3,
                                        const float* __restrict__ w,
                                        const float* __restrict__ bb,
                                        ushort_t* __restrict__ out16,
                                        ushort_t* __restrict__ out16l,
                                        float* red) {
    float4* xr = (float4*)(x + (size_t)row * D_);
    float4 v = xr[threadIdx.x];
    if (p0) {
        float4 b = ((const float4*)(p0 + (size_t)row * D_))[threadIdx.x];
        float4 c = ((const float4*)(p1 + (size_t)row * D_))[threadIdx.x];
        v.x += b.x + c.x; v.y += b.y + c.y; v.z += b.z + c.z; v.w += b.w + c.w;
        if (p2) {
            float4 d = ((const float4*)(p2 + (size_t)row * D_))[threadIdx.x];
            float4 e = ((const float4*)(p3 + (size_t)row * D_))[threadIdx.x];
            v.x += d.x + e.x; v.y += d.y + e.y;
            v.z += d.z + e.z; v.w += d.w + e.w;
        }
        xr[threadIdx.x] = v;
    }
    float s = v.x + v.y + v.z + v.w;
    #pragma unroll
    for (int off = 32; off; off >>= 1) s += __shfl_xor(s, off);
    int wave = threadIdx.x >> 6, lane = threadIdx.x & 63;
    if (lane == 0) red[wave] = s;
    __syncthreads();
    float m = (red[0] + red[1] + red[2] + red[3]) * (1.f / 1024.f);
    float dx = v.x - m, dy = v.y - m, dz = v.z - m, dw = v.w - m;
    float ss = dx*dx + dy*dy + dz*dz + dw*dw;
    #pragma unroll
    for (int off = 32; off; off >>= 1) ss += __shfl_xor(ss, off);
    __syncthreads();
    if (lane == 0) red[wave] = ss;
    __syncthreads();
    float var = (red[0] + red[1] + red[2] + red[3]) * (1.f / 1024.f);
    float inv = 1.f / (var + 1e-12f);
    float4 wv = ((const float4*)w)[threadIdx.x];
    float4 bv = ((const float4*)bb)[threadIdx.x];
    float4 ov;
    ov.x = wv.x * dx * inv + bv.x;
    ov.y = wv.y * dy * inv + bv.y;
    ov.z = wv.z * dz * inv + bv.z;
    ov.w = wv.w * dw * inv + bv.w;
    ushort4 oh;
    oh.x = f2bf(ov.x); oh.y = f2bf(ov.y); oh.z = f2bf(ov.z); oh.w = f2bf(ov.w);
    ((ushort4*)(out16 + (size_t)row * D_))[threadIdx.x] = oh;
    if (out16l) {
        ushort4 ol;
        ol.x = f2bf(ov.x - bf2f(oh.x));
        ol.y = f2bf(ov.y - bf2f(oh.y));
        ol.z = f2bf(ov.z - bf2f(oh.z));
        ol.w = f2bf(ov.w - bf2f(oh.w));
        ((ushort4*)(out16l + (size_t)row * D_))[threadIdx.x] = ol;
    }
}

// weight transpose fp32->bf16 (optional lo residual output)
__device__ __forceinline__ void wt_body(int tile, const float* __restrict__ W,
                                        ushort_t* __restrict__ Wt,
                                        ushort_t* __restrict__ Wtl,
                                        int K, int N, float (*t)[33]) {
    int nT = N >> 5;
    int n0 = (tile % nT) << 5, k0 = (tile / nT) << 5;
    int r = threadIdx.x >> 3, c4 = (threadIdx.x & 7) << 2;
    float4 v = *(const float4*)(W + (size_t)(k0 + r) * N + n0 + c4);
    t[r][c4+0] = v.x; t[r][c4+1] = v.y; t[r][c4+2] = v.z; t[r][c4+3] = v.w;
    __syncthreads();
    float v0 = t[c4+0][r], v1 = t[c4+1][r], v2 = t[c4+2][r], v3 = t[c4+3][r];
    ushort4 oh;
    oh.x = f2bf(v0); oh.y = f2bf(v1); oh.z = f2bf(v2); oh.w = f2bf(v3);
    size_t off = (size_t)(n0 + r) * K + k0 + c4;
    *(ushort4*)(Wt + off) = oh;
    if (Wtl) {
        ushort4 ol;
        ol.x = f2bf(v0 - bf2f(oh.x));
        ol.y = f2bf(v1 - bf2f(oh.y));
        ol.z = f2bf(v2 - bf2f(oh.z));
        ol.w = f2bf(v3 - bf2f(oh.w));
        *(ushort4*)(Wtl + off) = ol;
    }
}

// v [bh][s][64] -> vT [bh][d][s]
__device__ __forceinline__ void vt_body(int blk, const ushort_t* __restrict__ vb,
                                        ushort_t* __restrict__ vtb,
                                        ushort_t (*t)[72]) {
    int st = blk & 15, bh = blk >> 4;
    int tid = threadIdx.x;
    int sr = tid >> 2, c0 = (tid & 3) * 16;
    const ushort_t* src = vb + ((size_t)bh*S_ + st*64 + sr) * 64 + c0;
    *(uint4*)&t[sr][c0]     = *(const uint4*)src;
    *(uint4*)&t[sr][c0 + 8] = *(const uint4*)(src + 8);
    __syncthreads();
    int d = tid >> 2, s0 = (tid & 3) * 16;
    ushort_t vo[16];
    #pragma unroll
    for (int u = 0; u < 16; ++u) vo[u] = t[s0+u][d];
    size_t vout = ((size_t)bh*64 + d) * S_ + st*64 + s0;
    *(uint4*)(vtb + vout)     = *(uint4*)&vo[0];
    *(uint4*)(vtb + vout + 8) = *(uint4*)&vo[8];
}

// ------------------------------------------- fused: LN(+reduce) + up to two wt's
__global__ __launch_bounds__(256) void ln_wt_k(
    float* __restrict__ x,
    const float* __restrict__ p0, const float* __restrict__ p1,
    const float* __restrict__ p2, const float* __restrict__ p3,
    const float* __restrict__ lnw, const float* __restrict__ lnb,
    ushort_t* __restrict__ out16, ushort_t* __restrict__ out16l,
    const float* __restrict__ Wa, ushort_t* __restrict__ WaT,
    ushort_t* __restrict__ WaTl, int Ka, int Na,
    const float* __restrict__ Wb, ushort_t* __restrict__ WbT, int Kb, int Nb)
{
    __shared__ __align__(16) char sh[4352];
    int bid = blockIdx.x;
    if (bid < M_) {
        ln_body(bid, x, p0, p1, p2, p3, lnw, lnb, out16, out16l, (float*)sh);
    } else {
        bid -= M_;
        int tilesA = (Ka >> 5) * (Na >> 5);
        if (bid < tilesA) {
            wt_body(bid, Wa, WaT, WaTl, Ka, Na, (float(*)[33])sh);
        } else {
            wt_body(bid - tilesA, Wb, WbT, nullptr, Kb, Nb, (float(*)[33])sh);
        }
    }
}

// ------------------------------------------- fused: vt + wt(Wo)
__global__ __launch_bounds__(256) void vt_wt_k(
    const ushort_t* __restrict__ vb, ushort_t* __restrict__ vtb,
    const float* __restrict__ W, ushort_t* __restrict__ Wt, int K, int N)
{
    __shared__ __align__(16) char sh[9216];
    int bid = blockIdx.x;
    if (bid < B_*H_*(S_/64)) {
        vt_body(bid, vb, vtb, (ushort_t(*)[72])sh);
    } else {
        wt_body(bid - B_*H_*(S_/64), W, Wt, nullptr, K, N, (float(*)[33])sh);
    }
}

// ------------------------------------------- bf16 MFMA flash attn (layers>=1)
__global__ __launch_bounds__(256) void attn_mfma_k(const ushort_t* __restrict__ qb,
                                                   const ushort_t* __restrict__ kb,
                                                   const ushort_t* __restrict__ vtb,
                                                   ushort_t* __restrict__ o) {
    __shared__ __align__(16) char Kl[16384];   // [128 key][128B]
    __shared__ __align__(16) char Vl[16384];   // [64 d][256B]
    __shared__ __align__(16) char Pl[16384];   // 4 waves x [16 q][256B]
    int blk = blockIdx.x;
    int qt = 15 - (blk & 15);            // longest first
    int bh = blk >> 4;
    int hh = bh & 15, bb = bh >> 4;
    int tid = threadIdx.x, w = tid >> 6, lane = tid & 63;
    int lg = lane >> 4, lr = lane & 15;

    const ushort_t* qhb = qb + ((size_t)bh*S_ + qt*64 + w*16 + lr) * 64;
    bf16x8_t aq0 = *(const bf16x8_t*)(qhb + lg*8);
    bf16x8_t aq1 = *(const bf16x8_t*)(qhb + 32 + lg*8);

    f32x4_t oacc[4];
    #pragma unroll
    for (int n = 0; n < 4; ++n) oacc[n] = (f32x4_t){0.f,0.f,0.f,0.f};
    float m[4] = {-3.0e38f,-3.0e38f,-3.0e38f,-3.0e38f};
    float l[4] = {0.f,0.f,0.f,0.f};

    int kr = tid >> 1;
    int kboff = (tid & 1) * 64;
    int vd = tid >> 2;
    int vboff = (tid & 3) * 64;
    const ushort_t* kg = kb  + (size_t)bh * S_ * 64;
    const ushort_t* vg = vtb + (size_t)bh * 64 * S_;

    int ktl = qt >> 1;
    for (int kt = 0; kt <= ktl; ++kt) {
        __syncthreads();
        {
            const ushort_t* src = kg + (size_t)(kt*128 + kr) * 64 + kboff/2;
            uint4 a0 = *(const uint4*)(src);
            uint4 a1 = *(const uint4*)(src + 8);
            uint4 a2 = *(const uint4*)(src + 16);
            uint4 a3 = *(const uint4*)(src + 24);
            int kbase = kr*128 + kboff;
            int kswz = (kr & 7) << 4;
            *(uint4*)(Kl + ((kbase +  0) ^ kswz)) = a0;
            *(uint4*)(Kl + ((kbase + 16) ^ kswz)) = a1;
            *(uint4*)(Kl + ((kbase + 32) ^ kswz)) = a2;
            *(uint4*)(Kl + ((kbase + 48) ^ kswz)) = a3;
            const ushort_t* vs = vg + (size_t)vd * S_ + kt*128 + vboff/2;
            uint4 b0 = *(const uint4*)(vs);
            uint4 b1 = *(const uint4*)(vs + 8);
            uint4 b2 = *(const uint4*)(vs + 16);
            uint4 b3 = *(const uint4*)(vs + 24);
            int vbase = vd*256 + vboff;
            int vswz = (vd & 7) << 4;
            *(uint4*)(Vl + ((vbase +  0) ^ vswz)) = b0;
            *(uint4*)(Vl + ((vbase + 16) ^ vswz)) = b1;
            *(uint4*)(Vl + ((vbase + 32) ^ vswz)) = b2;
            *(uint4*)(Vl + ((vbase + 48) ^ vswz)) = b3;
        }
        __syncthreads();

        f32x4_t sfr[8];
        #pragma unroll
        for (int n = 0; n < 8; ++n) sfr[n] = (f32x4_t){0.f,0.f,0.f,0.f};
        __builtin_amdgcn_s_setprio(1);
        #pragma unroll
        for (int n = 0; n < 8; ++n) {
            int row = n*16 + lr;
            int swz = (row & 7) << 4;
            bf16x8_t b0 = *(const bf16x8_t*)(Kl + ((row*128 + lg*16) ^ swz));
            bf16x8_t b1 = *(const bf16x8_t*)(Kl + ((row*128 + 64 + lg*16) ^ swz));
            sfr[n] = __builtin_amdgcn_mfma_f32_16x16x32_bf16(aq0, b0, sfr[n], 0,0,0);
            sfr[n] = __builtin_amdgcn_mfma_f32_16x16x32_bf16(aq1, b1, sfr[n], 0,0,0);
        }
        __builtin_amdgcn_s_setprio(0);

        if (kt == ktl) {
            #pragma unroll
            for (int n = 0; n < 8; ++n) {
                int key = kt*128 + n*16 + lr;
                #pragma unroll
                for (int j = 0; j < 4; ++j) {
                    int qrow = qt*64 + w*16 + lg*4 + j;
                    if (key > qrow) sfr[n][j] = -3.0e38f;
                }
            }
        }

        float sc[4];
        #pragma unroll
        for (int j = 0; j < 4; ++j) {
            float v = sfr[0][j];
            #pragma unroll
            for (int n = 1; n < 8; ++n) v = fmaxf(v, sfr[n][j]);
            v = fmaxf(v, __shfl_xor(v, 1));
            v = fmaxf(v, __shfl_xor(v, 2));
            v = fmaxf(v, __shfl_xor(v, 4));
            v = fmaxf(v, __shfl_xor(v, 8));
            float mn = fmaxf(m[j], v);
            sc[j] = __expf(m[j] - mn);
            m[j] = mn;
        }
        #pragma unroll
        for (int n = 0; n < 8; ++n)
            #pragma unroll
            for (int j = 0; j < 4; ++j)
                sfr[n][j] = __expf(sfr[n][j] - m[j]);
        #pragma unroll
        for (int j = 0; j < 4; ++j) {
            float s = sfr[0][j];
            #pragma unroll
            for (int n = 1; n < 8; ++n) s += sfr[n][j];
            s += __shfl_xor(s, 1);
            s += __shfl_xor(s, 2);
            s += __shfl_xor(s, 4);
            s += __shfl_xor(s, 8);
            l[j] = l[j] * sc[j] + s;
            #pragma unroll
            for (int n = 0; n < 4; ++n) oacc[n][j] *= sc[j];
        }

        #pragma unroll
        for (int n = 0; n < 8; ++n) {
            #pragma unroll
            for (int j = 0; j < 4; ++j) {
                int row = lg*4 + j;
                int byt = (w*4096 + row*256 + (n*16 + lr)*2) ^ ((row & 7) << 4);
                *(ushort_t*)(Pl + byt) = f2bf(sfr[n][j]);
            }
        }
        int pswz = (lr & 7) << 4;
        bf16x8_t pa0 = *(const bf16x8_t*)(Pl + ((w*4096 + lr*256 +   0 + lg*16) ^ pswz));
        bf16x8_t pa1 = *(const bf16x8_t*)(Pl + ((w*4096 + lr*256 +  64 + lg*16) ^ pswz));
        bf16x8_t pa2 = *(const bf16x8_t*)(Pl + ((w*4096 + lr*256 + 128 + lg*16) ^ pswz));
        bf16x8_t pa3 = *(const bf16x8_t*)(Pl + ((w*4096 + lr*256 + 192 + lg*16) ^ pswz));

        __builtin_amdgcn_s_setprio(1);
        #pragma unroll
        for (int n = 0; n < 4; ++n) {
            int row = n*16 + lr;
            int swz = (row & 7) << 4;
            bf16x8_t v0 = *(const bf16x8_t*)(Vl + ((row*256 +   0 + lg*16) ^ swz));
            bf16x8_t v1 = *(const bf16x8_t*)(Vl + ((row*256 +  64 + lg*16) ^ swz));
            bf16x8_t v2 = *(const bf16x8_t*)(Vl + ((row*256 + 128 + lg*16) ^ swz));
            bf16x8_t v3 = *(const bf16x8_t*)(Vl + ((row*256 + 192 + lg*16) ^ swz));
            oacc[n] = __builtin_amdgcn_mfma_f32_16x16x32_bf16(pa0, v0, oacc[n], 0,0,0);
            oacc[n] = __builtin_amdgcn_mfma_f32_16x16x32_bf16(pa1, v1, oacc[n], 0,0,0);
            oacc[n] = __builtin_amdgcn_mfma_f32_16x16x32_bf16(pa2, v2, oacc[n], 0,0,0);
            oacc[n] = __builtin_amdgcn_mfma_f32_16x16x32_bf16(pa3, v3, oacc[n], 0,0,0);
        }
        __builtin_amdgcn_s_setprio(0);
    }

    #pragma unroll
    for (int j = 0; j < 4; ++j) {
        float rl = 1.f / l[j];
        int row = qt*64 + w*16 + lg*4 + j;
        size_t base = (size_t)(bb*S_ + row) * D_ + hh*64;
        #pragma unroll
        for (int n = 0; n < 4; ++n)
            o[base + n*16 + lr] = f2bf(oacc[n][j] * rl);
    }
}

// ------------------------------------------- split-precision MFMA attn, layer 0
__global__ __launch_bounds__(256) void attn_mfma0_k(const ushort_t* __restrict__ qhp,
                                                    const ushort_t* __restrict__ qlp,
                                                    const ushort_t* __restrict__ khp,
                                                    const ushort_t* __restrict__ klp,
                                                    const ushort_t* __restrict__ vtb,
                                                    ushort_t* __restrict__ o) {
    __shared__ __align__(16) char Khl[8192];
    __shared__ __align__(16) char Kll[8192];
    __shared__ __align__(16) char Vl[8192];
    __shared__ __align__(16) char Pl[8192];
    int blk = blockIdx.x;
    int qt = 15 - (blk & 15);
    int bh = blk >> 4;
    int hh = bh & 15, bb = bh >> 4;
    int tid = threadIdx.x, w = tid >> 6, lane = tid & 63;
    int lg = lane >> 4, lr = lane & 15;

    size_t qoff = ((size_t)bh*S_ + qt*64 + w*16 + lr) * 64;
    bf16x8_t aqh0 = *(const bf16x8_t*)(qhp + qoff + lg*8);
    bf16x8_t aqh1 = *(const bf16x8_t*)(qhp + qoff + 32 + lg*8);
    bf16x8_t aql0 = *(const bf16x8_t*)(qlp + qoff + lg*8);
    bf16x8_t aql1 = *(const bf16x8_t*)(qlp + qoff + 32 + lg*8);

    f32x4_t oacc[4];
    #pragma unroll
    for (int n = 0; n < 4; ++n) oacc[n] = (f32x4_t){0.f,0.f,0.f,0.f};
    float m[4] = {-3.0e38f,-3.0e38f,-3.0e38f,-3.0e38f};
    float l[4] = {0.f,0.f,0.f,0.f};

    int srow = tid >> 2;
    int soff = (tid & 3) * 32;
    const ushort_t* kgh = khp + (size_t)bh * S_ * 64;
    const ushort_t* kgl = klp + (size_t)bh * S_ * 64;
    const ushort_t* vg  = vtb + (size_t)bh * 64 * S_;

    for (int kt = 0; kt <= qt; ++kt) {
        __syncthreads();
        {
            int b0 = (srow*128 + soff) ^ ((srow & 7) << 4);
            int b1 = (srow*128 + soff + 16) ^ ((srow & 7) << 4);
            const ushort_t* src = kgh + (size_t)(kt*64 + srow) * 64 + soff/2;
            *(uint4*)(Khl + b0) = *(const uint4*)src;
            *(uint4*)(Khl + b1) = *(const uint4*)(src + 8);
            const ushort_t* srl = kgl + (size_t)(kt*64 + srow) * 64 + soff/2;
            *(uint4*)(Kll + b0) = *(const uint4*)srl;
            *(uint4*)(Kll + b1) = *(const uint4*)(srl + 8);
            const ushort_t* vs = vg + (size_t)srow * S_ + kt*64 + soff/2;
            *(uint4*)(Vl + b0) = *(const uint4*)vs;
            *(uint4*)(Vl + b1) = *(const uint4*)(vs + 8);
        }
        __syncthreads();

        f32x4_t sfr[4];
        #pragma unroll
        for (int n = 0; n < 4; ++n) sfr[n] = (f32x4_t){0.f,0.f,0.f,0.f};
        __builtin_amdgcn_s_setprio(1);
        #pragma unroll
        for (int n = 0; n < 4; ++n) {
            int row = n*16 + lr;
            int swz = (row & 7) << 4;
            bf16x8_t bh0 = *(const bf16x8_t*)(Khl + ((row*128 + lg*16) ^ swz));
            bf16x8_t bh1 = *(const bf16x8_t*)(Khl + ((row*128 + 64 + lg*16) ^ swz));
            bf16x8_t bl0 = *(const bf16x8_t*)(Kll + ((row*128 + lg*16) ^ swz));
            bf16x8_t bl1 = *(const bf16x8_t*)(Kll + ((row*128 + 64 + lg*16) ^ swz));
            sfr[n] = __builtin_amdgcn_mfma_f32_16x16x32_bf16(aqh0, bh0, sfr[n], 0,0,0);
            sfr[n] = __builtin_amdgcn_mfma_f32_16x16x32_bf16(aqh1, bh1, sfr[n], 0,0,0);
            sfr[n] = __builtin_amdgcn_mfma_f32_16x16x32_bf16(aqh0, bl0, sfr[n], 0,0,0);
            sfr[n] = __builtin_amdgcn_mfma_f32_16x16x32_bf16(aqh1, bl1, sfr[n], 0,0,0);
            sfr[n] = __builtin_amdgcn_mfma_f32_16x16x32_bf16(aql0, bh0, sfr[n], 0,0,0);
            sfr[n] = __builtin_amdgcn_mfma_f32_16x16x32_bf16(aql1, bh1, sfr[n], 0,0,0);
        }
        __builtin_amdgcn_s_setprio(0);

        if (kt == qt) {
            #pragma unroll
            for (int n = 0; n < 4; ++n) {
                int key = n*16 + lr;
                #pragma unroll
                for (int j = 0; j < 4; ++j) {
                    int qrow = w*16 + lg*4 + j;
                    if (key > qrow) sfr[n][j] = -3.0e38f;
                }
            }
        }

        float sc[4];
        #pragma unroll
        for (int j = 0; j < 4; ++j) {
            float v = fmaxf(fmaxf(sfr[0][j], sfr[1][j]), fmaxf(sfr[2][j], sfr[3][j]));
            v = fmaxf(v, __shfl_xor(v, 1));
            v = fmaxf(v, __shfl_xor(v, 2));
            v = fmaxf(v, __shfl_xor(v, 4));
            v = fmaxf(v, __shfl_xor(v, 8));
            float mn = fmaxf(m[j], v);
            sc[j] = __expf(m[j] - mn);
            m[j] = mn;
        }
        #pragma unroll
        for (int n = 0; n < 4; ++n)
            #pragma unroll
            for (int j = 0; j < 4; ++j)
                sfr[n][j] = __expf(sfr[n][j] - m[j]);
        #pragma unroll
        for (int j = 0; j < 4; ++j) {
            float s = sfr[0][j] + sfr[1][j] + sfr[2][j] + sfr[3][j];
            s += __shfl_xor(s, 1);
            s += __shfl_xor(s, 2);
            s += __shfl_xor(s, 4);
            s += __shfl_xor(s, 8);
            l[j] = l[j] * sc[j] + s;
            #pragma unroll
            for (int n = 0; n < 4; ++n) oacc[n][j] *= sc[j];
        }

        #pragma unroll
        for (int n = 0; n < 4; ++n) {
            #pragma unroll
            for (int j = 0; j < 4; ++j) {
                int row = lg*4 + j;
                int byt = (w*2048 + row*128 + (n*16 + lr)*2) ^ ((row & 7) << 4);
                *(ushort_t*)(Pl + byt) = f2bf(sfr[n][j]);
            }
        }
        int pswz = (lr & 7) << 4;
        bf16x8_t pa0 = *(const bf16x8_t*)(Pl + ((w*2048 + lr*128 + lg*16) ^ pswz));
        bf16x8_t pa1 = *(const bf16x8_t*)(Pl + ((w*2048 + lr*128 + 64 + lg*16) ^ pswz));

        __builtin_amdgcn_s_setprio(1);
        #pragma unroll
        for (int n = 0; n < 4; ++n) {
            int row = n*16 + lr;
            int swz = (row & 7) << 4;
            bf16x8_t v0 = *(const bf16x8_t*)(Vl + ((row*128 + lg*16) ^ swz));
            bf16x8_t v1 = *(const bf16x8_t*)(Vl + ((row*128 + 64 + lg*16) ^ swz));
            oacc[n] = __builtin_amdgcn_mfma_f32_16x16x32_bf16(pa0, v0, oacc[n], 0,0,0);
            oacc[n] = __builtin_amdgcn_mfma_f32_16x16x32_bf16(pa1, v1, oacc[n], 0,0,0);
        }
        __builtin_amdgcn_s_setprio(0);
    }

    #pragma unroll
    for (int j = 0; j < 4; ++j) {
        float rl = 1.f / l[j];
        int row = qt*64 + w*16 + lg*4 + j;
        size_t base = (size_t)(bb*S_ + row) * D_ + hh*64;
        #pragma unroll
        for (int n = 0; n < 4; ++n)
            o[base + n*16 + lr] = f2bf(oacc[n][j] * rl);
    }
}

// ---------------------------------------------------------------- GEMM bf16
__device__ __forceinline__ float gelu_f(float x) {
    return 0.5f * x * (1.f + erff(x * 0.70710678118654752f));
}

// 128x128 tile, 4 waves (2x2). T2 XOR-swizzled LDS; transpose epilogue.
// epi: 0 = fp32 out, 1 = fp32 + Res, 2 = gelu->bf16
template<int TM>
__global__ __launch_bounds__(2*TM, 4) void gemm_bf16_k(
    const ushort_t* __restrict__ A,
    const ushort_t* __restrict__ Bt,
    const float* __restrict__ Res,
    float* __restrict__ Cf,
    ushort_t* __restrict__ Cb,
    int M, int N, int K, int epi)
{
    __shared__ __align__(16) char smem[TM*128 + 128*128];  // As | Bs (bytes)
    ushort_t* As = (ushort_t*)smem;
    ushort_t* Bs = (ushort_t*)(smem + TM*128);
    int tid = threadIdx.x;
    int wid = tid >> 6, lane = tid & 63;
    int wm = wid >> 1;
    int wn = wid & 1;
    int bm = blockIdx.x * TM, bn = blockIdx.y * 128;

    f32x4_t acc[4][4];
    #pragma unroll
    for (int m = 0; m < 4; ++m)
        #pragma unroll
        for (int n = 0; n < 4; ++n)
            acc[m][n] = (f32x4_t){0.f, 0.f, 0.f, 0.f};

    int srow = (lane >> 3);
    int scol = (((lane & 7) ^ (lane >> 3)) * 8);   // pre-swizzled source chunk

    for (int k0 = 0; k0 < K; k0 += 64) {
        __syncthreads();
        #pragma unroll
        for (int i = 0; i < 4; ++i) {
            int rb = i * (TM/4) + wid * 8;
            gload_lds16(A + (size_t)(bm + rb + srow) * K + k0 + scol, &As[rb * 64]);
        }
        #pragma unroll
        for (int i = 0; i < 4; ++i) {
            int rb = i * 32 + wid * 8;
            gload_lds16(Bt + (size_t)(bn + rb + srow) * K + k0 + scol, &Bs[rb * 64]);
        }
        __syncthreads();
        #pragma unroll
        for (int kk = 0; kk < 64; kk += 32) {
            bf16x8_t af[4], bfr[4];
            int kof = kk + (lane >> 4) * 8;
            #pragma unroll
            for (int m = 0; m < 4; ++m) {
                int r = wm * 64 + m * 16 + (lane & 15);
                af[m] = *(const bf16x8_t*)&As[(r * 64 + kof) ^ ((r & 7) << 3)];
            }
            #pragma unroll
            for (int n = 0; n < 4; ++n) {
                int r = wn * 64 + n * 16 + (lane & 15);
                bfr[n] = *(const bf16x8_t*)&Bs[(r * 64 + kof) ^ ((r & 7) << 3)];
            }
            #pragma unroll
            for (int m = 0; m < 4; ++m)
                #pragma unroll
                for (int n = 0; n < 4; ++n)
                    acc[m][n] = __builtin_amdgcn_mfma_f32_16x16x32_bf16(
                        af[m], bfr[n], acc[m][n], 0, 0, 0);
        }
    }

    // ---- epilogue: LDS fragment transpose, full-line stores ----
    __syncthreads();
    float* scr = (float*)smem + (size_t)wid * 1088;   // 16 rows x 68 (padded)
    int cr = (lane >> 4) * 4, cc = lane & 15;
    #pragma unroll
    for (int m = 0; m < 4; ++m) {
        #pragma unroll
        for (int n = 0; n < 4; ++n)
            #pragma unroll
            for (int j = 0; j < 4; ++j)
                scr[(cr + j) * 68 + n * 16 + cc] = acc[m][n][j];
        #pragma unroll
        for (int i = 0; i < 4; ++i) {
            int rr = i * 4 + (lane >> 4);
            int c2 = (lane & 15) * 4;
            float4 v = *(float4*)&scr[rr * 68 + c2];
            int row = bm + wm * 64 + m * 16 + rr;
            int col = bn + wn * 64 + c2;
            size_t off = (size_t)row * N + col;
            if (epi == 0) {
                *(float4*)&Cf[off] = v;
            } else if (epi == 1) {
                float4 r4 = *(const float4*)&Res[off];
                v.x += r4.x; v.y += r4.y; v.z += r4.z; v.w += r4.w;
                *(float4*)&Cf[off] = v;
            } else {
                ushort4 o4;
                o4.x = f2bf(gelu_f(v.x)); o4.y = f2bf(gelu_f(v.y));
                o4.z = f2bf(gelu_f(v.z)); o4.w = f2bf(gelu_f(v.w));
                *(ushort4*)&Cb[off] = o4;
            }
        }
    }
}

// 256x128 tile, 4 waves each 64x128 (acc[4][8]) -- decode GEMM.
// 1-D grid + XCD swizzle (T1); NT full-line C stores.
__global__ __launch_bounds__(256, 2) void gemm256_k(
    const ushort_t* __restrict__ A,
    const ushort_t* __restrict__ Bt,
    float* __restrict__ Cf,
    int M, int N, int K)
{
    __shared__ __align__(16) char smem[256*128 + 128*128];  // As 32KB | Bs 16KB
    ushort_t* As = (ushort_t*)smem;
    ushort_t* Bs = (ushort_t*)(smem + 256*128);
    int tid = threadIdx.x;
    int wid = tid >> 6, lane = tid & 63;
    int bid = blockIdx.x;
    int nPerXcd = (M >> 8) * (N >> 7) / 8;          // 2000/8 = 250
    int wg = (bid & 7) * nPerXcd + (bid >> 3);
    int bm = (wg & 7) * 256;
    int bn = (wg >> 3) * 128;

    f32x4_t acc[4][8];
    #pragma unroll
    for (int m = 0; m < 4; ++m)
        #pragma unroll
        for (int n = 0; n < 8; ++n)
            acc[m][n] = (f32x4_t){0.f, 0.f, 0.f, 0.f};

    int srow = (lane >> 3);
    int scol = (((lane & 7) ^ (lane >> 3)) * 8);

    for (int k0 = 0; k0 < K; k0 += 64) {
        __syncthreads();
        #pragma unroll
        for (int i = 0; i < 8; ++i) {
            int rb = i * 32 + wid * 8;
            gload_lds16(A + (size_t)(bm + rb + srow) * K + k0 + scol, &As[rb * 64]);
        }
        #pragma unroll
        for (int i = 0; i < 4; ++i) {
            int rb = i * 32 + wid * 8;
            gload_lds16(Bt + (size_t)(bn + rb + srow) * K + k0 + scol, &Bs[rb * 64]);
        }
        __syncthreads();
        #pragma unroll
        for (int kk = 0; kk < 64; kk += 32) {
            bf16x8_t af[4], bfr[8];
            int kof = kk + (lane >> 4) * 8;
            #pragma unroll
            for (int m = 0; m < 4; ++m) {
                int r = wid * 64 + m * 16 + (lane & 15);
                af[m] = *(const bf16x8_t*)&As[(r * 64 + kof) ^ ((r & 7) << 3)];
            }
            #pragma unroll
            for (int n = 0; n < 8; ++n) {
                int r = n * 16 + (lane & 15);
                bfr[n] = *(const bf16x8_t*)&Bs[(r * 64 + kof) ^ ((r & 7) << 3)];
            }
            #pragma unroll
            for (int m = 0; m < 4; ++m)
                #pragma unroll
                for (int n = 0; n < 8; ++n)
                    acc[m][n] = __builtin_amdgcn_mfma_f32_16x16x32_bf16(
                        af[m], bfr[n], acc[m][n], 0, 0, 0);
        }
    }

    // epilogue: per-wave 16x68 scratch, two 64-col halves; NT full-line stores
    __syncthreads();
    float* scr = (float*)smem + (size_t)wid * 1088;
    int cr = (lane >> 4) * 4, cc = lane & 15;
    #pragma unroll
    for (int m = 0; m < 4; ++m) {
        #pragma unroll
        for (int half = 0; half < 2; ++half) {
            #pragma unroll
            for (int n = 0; n < 4; ++n)
                #pragma unroll
                for (int j = 0; j < 4; ++j)
                    scr[(cr + j) * 68 + n * 16 + cc] = acc[m][half*4 + n][j];
            #pragma unroll
            for (int i = 0; i < 4; ++i) {
                int rr = i * 4 + (lane >> 4);
                int c2 = (lane & 15) * 4;
                f32x4_t v = *(f32x4_t*)&scr[rr * 68 + c2];
                int row = bm + wid * 64 + m * 16 + rr;
                int col = bn + half * 64 + c2;
                __builtin_nontemporal_store(v, (f32x4_t*)&Cf[(size_t)row * N + col]);
            }
        }
    }
}

// 64x128 tile, 4 waves each 64x32 (acc[4][2]) -- small-grid Wo/W2 GEMMs.
// Split-K via gridDim.z: each z computes K/nz inner slice, writes fp32 partial
// at Cf + z*M*N (epi=0). >=2 blocks/CU covers the barrier-drain stall.
__global__ __launch_bounds__(256, 4) void gemm64_k(
    const ushort_t* __restrict__ A,
    const ushort_t* __restrict__ Bt,
    const float* __restrict__ Res,
    float* __restrict__ Cf,
    ushort_t* __restrict__ Cb,
    int M, int N, int K, int epi)
{
    __shared__ __align__(16) char smem[64*128 + 128*128];  // As 8KB | Bs 16KB
    ushort_t* As = (ushort_t*)smem;
    ushort_t* Bs = (ushort_t*)(smem + 64*128);
    int tid = threadIdx.x;
    int wid = tid >> 6, lane = tid & 63;
    int bm = blockIdx.x * 64, bn = blockIdx.y * 128;
    int z = blockIdx.z;
    int kPer = K / (int)gridDim.z;
    int kEnd = (z + 1) * kPer;

    f32x4_t acc[4][2];
    #pragma unroll
    for (int m = 0; m < 4; ++m)
        #pragma unroll
        for (int n = 0; n < 2; ++n)
            acc[m][n] = (f32x4_t){0.f, 0.f, 0.f, 0.f};

    int srow = (lane >> 3);
    int scol = (((lane & 7) ^ (lane >> 3)) * 8);

    for (int k0 = z * kPer; k0 < kEnd; k0 += 64) {
        __syncthreads();
        #pragma unroll
        for (int i = 0; i < 2; ++i) {
            int rb = i * 32 + wid * 8;
            gload_lds16(A + (size_t)(bm + rb + srow) * K + k0 + scol, &As[rb * 64]);
        }
        #pragma unroll
        for (int i = 0; i < 4; ++i) {
            int rb = i * 32 + wid * 8;
            gload_lds16(Bt + (size_t)(bn + rb + srow) * K + k0 + scol, &Bs[rb * 64]);
        }
        __syncthreads();
        #pragma unroll
        for (int kk = 0; kk < 64; kk += 32) {
            bf16x8_t af[4], bfr[2];
            int kof = kk + (lane >> 4) * 8;
            #pragma unroll
            for (int m = 0; m < 4; ++m) {
                int r = m * 16 + (lane & 15);
                af[m] = *(const bf16x8_t*)&As[(r * 64 + kof) ^ ((r & 7) << 3)];
            }
            #pragma unroll
            for (int n = 0; n < 2; ++n) {
                int r = wid * 32 + n * 16 + (lane & 15);
                bfr[n] = *(const bf16x8_t*)&Bs[(r * 64 + kof) ^ ((r & 7) << 3)];
            }
            #pragma unroll
            for (int m = 0; m < 4; ++m)
                #pragma unroll
                for (int n = 0; n < 2; ++n)
                    acc[m][n] = __builtin_amdgcn_mfma_f32_16x16x32_bf16(
                        af[m], bfr[n], acc[m][n], 0, 0, 0);
        }
    }

    // epilogue: per-wave 16x36 fp32 scratch, float4/ushort4 stores
    __syncthreads();
    float* scr = (float*)smem + (size_t)wid * 576;
    int cr = (lane >> 4) * 4, cc = lane & 15;
    size_t zoff = (size_t)z * M * N;
    #pragma unroll
    for (int m = 0; m < 4; ++m) {
        #pragma unroll
        for (int n = 0; n < 2; ++n)
            #pragma unroll
            for (int j = 0; j < 4; ++j)
                scr[(cr + j) * 36 + n * 16 + cc] = acc[m][n][j];
        #pragma unroll
        for (int i = 0; i < 2; ++i) {
            int rr = i * 8 + (lane >> 3);          // 0..15
            int c2 = (lane & 7) * 4;               // 0..28
            float4 v = *(float4*)&scr[rr * 36 + c2];
            int row = bm + m * 16 + rr;
            int col = bn + wid * 32 + c2;
            size_t off = (size_t)row * N + col;
            if (epi == 0) {
                *(float4*)&Cf[zoff + off] = v;
            } else if (epi == 1) {
                float4 r4 = *(const float4*)&Res[off];
                v.x += r4.x; v.y += r4.y; v.z += r4.z; v.w += r4.w;
                *(float4*)&Cf[off] = v;
            } else {
                ushort4 o4;
                o4.x = f2bf(gelu_f(v.x)); o4.y = f2bf(gelu_f(v.y));
                o4.z = f2bf(gelu_f(v.z)); o4.w = f2bf(gelu_f(v.w));
                *(ushort4*)&Cb[off] = o4;
            }
        }
    }
}

// ----------------------- QKV GEMM with fused RoPE + bf16 epilogue (layers>=1)
__global__ __launch_bounds__(256, 4) void gemm_qkv_k(
    const ushort_t* __restrict__ A,
    const ushort_t* __restrict__ Bt,
    ushort_t* __restrict__ qb, ushort_t* __restrict__ kb,
    ushort_t* __restrict__ vb)
{
    __shared__ __align__(16) ushort_t As[128 * 64];
    __shared__ __align__(16) ushort_t Bs[128 * 64];
    const int K = D_;
    int tid = threadIdx.x;
    int wid = tid >> 6, lane = tid & 63;
    int wm = wid >> 1, wn = wid & 1;
    int bm = blockIdx.x * 128, bn = blockIdx.y * 128;

    f32x4_t acc[4][4];
    #pragma unroll
    for (int m = 0; m < 4; ++m)
        #pragma unroll
        for (int n = 0; n < 4; ++n)
            acc[m][n] = (f32x4_t){0.f, 0.f, 0.f, 0.f};

    int srow = (lane >> 3);
    int scol = (((lane & 7) ^ (lane >> 3)) * 8);

    for (int k0 = 0; k0 < K; k0 += 64) {
        __syncthreads();
        #pragma unroll
        for (int i = 0; i < 4; ++i) {
            int rb = i * 32 + wid * 8;
            gload_lds16(A  + (size_t)(bm + rb + srow) * K + k0 + scol, &As[rb * 64]);
            gload_lds16(Bt + (size_t)(bn + rb + srow) * K + k0 + scol, &Bs[rb * 64]);
        }
        __syncthreads();
        #pragma unroll
        for (int kk = 0; kk < 64; kk += 32) {
            bf16x8_t af[4], bfr[4];
            int kof = kk + (lane >> 4) * 8;
            #pragma unroll
            for (int m = 0; m < 4; ++m) {
                int r = wm * 64 + m * 16 + (lane & 15);
                af[m] = *(const bf16x8_t*)&As[(r * 64 + kof) ^ ((r & 7) << 3)];
            }
            #pragma unroll
            for (int n = 0; n < 4; ++n) {
                int r = wn * 64 + n * 16 + (lane & 15);
                bfr[n] = *(const bf16x8_t*)&Bs[(r * 64 + kof) ^ ((r & 7) << 3)];
            }
            #pragma unroll
            for (int m = 0; m < 4; ++m)
                #pragma unroll
                for (int n = 0; n < 4; ++n)
                    acc[m][n] = __builtin_amdgcn_mfma_f32_16x16x32_bf16(
                        af[m], bfr[n], acc[m][n], 0, 0, 0);
        }
    }

    int cr = (lane >> 4) * 4, cc = lane & 15;
    float csn[4], snn[4];
    int partn[4], headn[4], dn[4];
    #pragma unroll
    for (int n = 0; n < 4; ++n) {
        int col = bn + wn*64 + n*16 + cc;
        int head = col / 192;
        int rem = col - head*192;
        partn[n] = rem >> 6;
        dn[n] = rem & 63;
        headn[n] = head;
        float inv = exp2f((float)(dn[n] >> 1) * (-13.287712379549449f / 32.f));
        sincosf((float)head * inv, &snn[n], &csn[n]);
    }
    bool odd = (lane & 1);
    #pragma unroll
    for (int m = 0; m < 4; ++m) {
        int row = bm + wm * 64 + m * 16 + cr;
        #pragma unroll
        for (int n = 0; n < 4; ++n) {
            ushort_t* dst = (partn[n] == 0) ? qb : (partn[n] == 1) ? kb : vb;
            #pragma unroll
            for (int j = 0; j < 4; ++j) {
                float a = acc[m][n][j];
                float p = __shfl_xor(a, 1);
                float outv;
                if (partn[n] == 2) outv = a;
                else {
                    outv = odd ? (p*snn[n] + a*csn[n]) : (a*csn[n] - p*snn[n]);
                    if (partn[n] == 0) outv *= 0.125f;
                }
                int r = row + j;
                size_t off = ((size_t)((r >> 10)*16 + headn[n]) * S_ + (r & 1023)) * 64 + dn[n];
                dst[off] = f2bf(outv);
            }
        }
    }
}

// -------------- layer-0: split-precision QKV GEMM + fused rope/split epilogue
__global__ __launch_bounds__(256, 2) void gemm_split_qkv_k(
    const ushort_t* __restrict__ Ah, const ushort_t* __restrict__ Al,
    const ushort_t* __restrict__ Bh, const ushort_t* __restrict__ Bl,
    ushort_t* __restrict__ qhb, ushort_t* __restrict__ qlb,
    ushort_t* __restrict__ khb, ushort_t* __restrict__ klb,
    ushort_t* __restrict__ vb)
{
    __shared__ __align__(16) ushort_t Ash[128 * 64];
    __shared__ __align__(16) ushort_t Asl[128 * 64];
    __shared__ __align__(16) ushort_t Bsh[128 * 64];
    __shared__ __align__(16) ushort_t Bsl[128 * 64];
    const int K = D_;
    int tid = threadIdx.x;
    int wid = tid >> 6, lane = tid & 63;
    int wm = wid >> 1, wn = wid & 1;
    int bm = blockIdx.x * 128, bn = blockIdx.y * 128;

    f32x4_t acc[4][4];
    #pragma unroll
    for (int m = 0; m < 4; ++m)
        #pragma unroll
        for (int n = 0; n < 4; ++n)
            acc[m][n] = (f32x4_t){0.f, 0.f, 0.f, 0.f};

    int srow = (lane >> 3);
    int scol = (((lane & 7) ^ (lane >> 3)) * 8);

    for (int k0 = 0; k0 < K; k0 += 64) {
        __syncthreads();
        #pragma unroll
        for (int i = 0; i < 4; ++i) {
            int rb = i * 32 + wid * 8;
            size_t ga = (size_t)(bm + rb + srow) * K + k0 + scol;
            size_t gb = (size_t)(bn + rb + srow) * K + k0 + scol;
            gload_lds16(Ah + ga, &Ash[rb * 64]);
            gload_lds16(Al + ga, &Asl[rb * 64]);
            gload_lds16(Bh + gb, &Bsh[rb * 64]);
            gload_lds16(Bl + gb, &Bsl[rb * 64]);
        }
        __syncthreads();
        #pragma unroll
        for (int kk = 0; kk < 64; kk += 32) {
            bf16x8_t ah[4], al[4], bhf[4], blf[4];
            int kof = kk + (lane >> 4) * 8;
            #pragma unroll
            for (int m = 0; m < 4; ++m) {
                int r = wm * 64 + m * 16 + (lane & 15);
                int ro = (r * 64 + kof) ^ ((r & 7) << 3);
                ah[m] = *(const bf16x8_t*)&Ash[ro];
                al[m] = *(const bf16x8_t*)&Asl[ro];
            }
            #pragma unroll
            for (int n = 0; n < 4; ++n) {
                int r = wn * 64 + n * 16 + (lane & 15);
                int ro = (r * 64 + kof) ^ ((r & 7) << 3);
                bhf[n] = *(const bf16x8_t*)&Bsh[ro];
                blf[n] = *(const bf16x8_t*)&Bsl[ro];
            }
            #pragma unroll
            for (int m = 0; m < 4; ++m)
                #pragma unroll
                for (int n = 0; n < 4; ++n) {
                    acc[m][n] = __builtin_amdgcn_mfma_f32_16x16x32_bf16(
                        ah[m], bhf[n], acc[m][n], 0, 0, 0);
                    acc[m][n] = __builtin_amdgcn_mfma_f32_16x16x32_bf16(
                        ah[m], blf[n], acc[m][n], 0, 0, 0);
                    acc[m][n] = __builtin_amdgcn_mfma_f32_16x16x32_bf16(
                        al[m], bhf[n], acc[m][n], 0, 0, 0);
                }
        }
    }

    int cr = (lane >> 4) * 4, cc = lane & 15;
    float csn[4], snn[4];
    int partn[4], headn[4], dn[4];
    #pragma unroll
    for (int n = 0; n < 4; ++n) {
        int col = bn + wn*64 + n*16 + cc;
        int head = col / 192;
        int rem = col - head*192;
        partn[n] = rem >> 6;
        dn[n] = rem & 63;
        headn[n] = head;
        float inv = exp2f((float)(dn[n] >> 1) * (-13.287712379549449f / 32.f));
        sincosf((float)head * inv, &snn[n], &csn[n]);
    }
    bool odd = (lane & 1);
    #pragma unroll
    for (int m = 0; m < 4; ++m) {
        int row = bm + wm * 64 + m * 16 + cr;
        #pragma unroll
        for (int n = 0; n < 4; ++n) {
            #pragma unroll
            for (int j = 0; j < 4; ++j) {
                float a = acc[m][n][j];
                float p = __shfl_xor(a, 1);
                int r = row + j;
                size_t off = ((size_t)((r >> 10)*16 + headn[n]) * S_ + (r & 1023)) * 64 + dn[n];
                if (partn[n] == 2) {
                    vb[off] = f2bf(a);
                } else {
                    float outv = odd ? (p*snn[n] + a*csn[n]) : (a*csn[n] - p*snn[n]);
                    if (partn[n] == 0) outv *= 0.125f;
                    ushort_t hi = f2bf(outv);
                    ushort_t lo = f2bf(outv - bf2f(hi));
                    if (partn[n] == 0) { qhb[off] = hi; qlb[off] = lo; }
                    else               { khb[off] = hi; klb[off] = lo; }
                }
            }
        }
    }
}

// ---------------------------------------------------------------- launch
extern "C" void kernel_launch(void* const* d_in, const int* in_sizes, int n_in,
                              void* d_out, int out_size, void* d_ws, size_t ws_size,
                              hipStream_t stream) {
    const int*   x    = (const int*)  d_in[0];
    const float* emb  = (const float*)d_in[1];
    const float* ln1w = (const float*)d_in[2];
    const float* ln1b = (const float*)d_in[3];
    const float* Wqkv = (const float*)d_in[4];
    const float* Wo   = (const float*)d_in[5];
    const float* ln2w = (const float*)d_in[6];
    const float* ln2b = (const float*)d_in[7];
    const float* W1   = (const float*)d_in[8];
    const float* W2   = (const float*)d_in[9];
    const float* lnfw = (const float*)d_in[10];
    const float* lnfb = (const float*)d_in[11];
    const float* Wdec = (const float*)d_in[12];
    float* out = (float*)d_out;

    // ---- workspace layout (bytes), lifetime-aliased, 80 MB total ----
    char* ws = (char*)d_ws;
    float*    h     = (float*)   (ws + 0);              // 8 MB  [2048,1024] f32
    ushort_t* xnb   = (ushort_t*)(ws + (8u<<20));       // 4 MB  LN out hi
    ushort_t* ob    = (ushort_t*)(ws + (12u<<20));      // 4 MB  attn out / xl (l=0)
    ushort_t* q_bf  = (ushort_t*)(ws + (16u<<20));      // 4 MB  q (qh for l=0)
    ushort_t* k_bf  = (ushort_t*)(ws + (20u<<20));      // 4 MB  k (kh for l=0)
    ushort_t* vT_bf = (ushort_t*)(ws + (24u<<20));      // 4 MB  vT
    ushort_t* v_bf  = (ushort_t*)(ws + (28u<<20));      // 4 MB  v row-major
    ushort_t* ql0   = (ushort_t*)(ws + (32u<<20));      // 4 MB  ql (l=0)
    ushort_t* kl0   = (ushort_t*)(ws + (36u<<20));      // 4 MB  kl (l=0)
    float*    pbuf  = (float*)   (ws + (16u<<20));      // up to 32 MB split-K
                                                        //  partials (16-48 MB,
                                                        //  all dead at use time)
    ushort_t* ffb   = (ushort_t*)(ws + (40u<<20));      // 16 MB [2048,4096] bf16
    ushort_t* wqkvT = (ushort_t*)(ws + (56u<<20));      // 6 MB  [3072,1024] bf16
    ushort_t* woT   = (ushort_t*)(ws + (62u<<20));      // 2 MB  [1024,1024] bf16
    ushort_t* w1T   = (ushort_t*)(ws + (64u<<20));      // 8 MB  [4096,1024] bf16
    ushort_t* w2T   = (ushort_t*)(ws + (72u<<20));      // 8 MB  [1024,4096] bf16
    ushort_t* wqkvTl= (ushort_t*)(ws + (64u<<20));      // 6 MB  (l=0 only, dead before wt(W1))
    ushort_t* wdecT = (ushort_t*)(ws + (16u<<20));      // 64 MB, aliases q_bf..w2T (post-loop)

    const int tQKV = (D_/32)*(3*D_/32);     // 3072
    const int tWo  = (D_/32)*(D_/32);       // 1024
    const int tW1  = (D_/32)*(DFF_/32);     // 4096
    const int tW2  = (DFF_/32)*(D_/32);     // 4096
    const int tDec = (D_/32)*(V_/32);       // 32000
    const int nVt  = B_*H_*(S_/64);         // 512
    float* pb1 = pbuf + (size_t)M_*D_;
    float* pb2 = pbuf + (size_t)2*M_*D_;
    float* pb3 = pbuf + (size_t)3*M_*D_;

    embed_k<<<M_, 256, 0, stream>>>(x, emb, h);
    for (int l = 0; l < L_; ++l) {
        // W2 partials of layer l-1 fuse into this ln1 (null for l==0)
        const float* rp0 = (l == 0) ? nullptr : pbuf;
        const float* rp1 = (l == 0) ? nullptr : pb1;
        if (l == 0) {
            ln_wt_k<<<M_ + tQKV, 256, 0, stream>>>(
                h, rp0, rp1, nullptr, nullptr, ln1w, ln1b, xnb, ob /*=xl*/,
                Wqkv, wqkvT, wqkvTl, D_, 3*D_, nullptr, nullptr, 0, 0);
            gemm_split_qkv_k<<<dim3(M_/128, 3*D_/128), 256, 0, stream>>>(
                xnb, ob /*=xl*/, wqkvT, wqkvTl, q_bf, ql0, k_bf, kl0, v_bf);
            vt_wt_k<<<nVt + tWo, 256, 0, stream>>>(
                v_bf, vT_bf, Wo + (size_t)l*D_*D_, woT, D_, D_);
            attn_mfma0_k<<<nVt, 256, 0, stream>>>(
                q_bf, ql0, k_bf, kl0, vT_bf, ob);
        } else {
            ln_wt_k<<<M_ + tQKV, 256, 0, stream>>>(
                h, rp0, rp1, nullptr, nullptr, ln1w + l*D_, ln1b + l*D_, xnb, nullptr,
                Wqkv + (size_t)l*D_*3*D_, wqkvT, nullptr, D_, 3*D_,
                nullptr, nullptr, 0, 0);
            gemm_qkv_k<<<dim3(M_/128, 3*D_/128), 256, 0, stream>>>(
                xnb, wqkvT, q_bf, k_bf, v_bf);
            vt_wt_k<<<nVt + tWo, 256, 0, stream>>>(
                v_bf, vT_bf, Wo + (size_t)l*D_*D_, woT, D_, D_);
            attn_mfma_k<<<nVt, 256, 0, stream>>>(q_bf, k_bf, vT_bf, ob);
        }
        // Wo GEMM: split-K=4 partials (16-48MB all dead: q..v, ql0/kl0,
        // prev ffb first half); 4-way reduce fused into ln2
        gemm64_k<<<dim3(M_/64, D_/128, 4), 256, 0, stream>>>(
            ob, woT, nullptr, pbuf, nullptr, M_, D_, D_, 0);
        ln_wt_k<<<M_ + tW1 + tW2, 256, 0, stream>>>(
            h, pbuf, pb1, pb2, pb3, ln2w + l*D_, ln2b + l*D_, xnb, nullptr,
            W1 + (size_t)l*D_*DFF_, w1T, nullptr, D_, DFF_,
            W2 + (size_t)l*DFF_*D_, w2T, DFF_, D_);
        gemm_bf16_k<128><<<dim3(M_/128, DFF_/128), 256, 0, stream>>>(
            xnb, w1T, nullptr, nullptr, ffb, M_, DFF_, D_, 2);
        // W2: split-K=2 only (z=3 partial would overlap ffb = W2's input A)
        gemm64_k<<<dim3(M_/64, D_/128, 2), 256, 0, stream>>>(
            ffb, w2T, nullptr, pbuf, nullptr, M_, D_, DFF_, 0);
        // reduce fuses into next layer's ln1 (or resadd before final LN)
    }
    // last W2 reduce must precede final ln_wt (wdecT overwrites pbuf region)
    resadd_k<<<M_*D_/1024, 256, 0, stream>>>(h, pbuf, pb1);
    ln_wt_k<<<M_ + tDec, 256, 0, stream>>>(
        h, nullptr, nullptr, nullptr, nullptr, lnfw, lnfb, xnb, nullptr,
        Wdec, wdecT, nullptr, D_, V_, nullptr, nullptr, 0, 0);
    gemm256_k<<<(M_/256)*(V_/128), 256, 0, stream>>>(
        xnb, wdecT, out, M_, V_, D_);
}

// Round 27
// 1469.070 us; speedup vs baseline: 1.0252x; 1.0252x over previous
//
#include <hip/hip_runtime.h>
#include <hip/hip_bf16.h>
#include <math.h>

#define B_ 2
#define S_ 1024
#define D_ 1024
#define H_ 16
#define HD_ 64
#define L_ 8
#define DFF_ 4096
#define V_ 32000
#define M_ (B_*S_)   /* 2048 rows */

typedef unsigned short ushort_t;
typedef __attribute__((ext_vector_type(8))) __bf16 bf16x8_t;
typedef __attribute__((ext_vector_type(4))) float f32x4_t;

__device__ __forceinline__ ushort_t f2bf(float f) {
    union { float f; unsigned u; } x; x.f = f;
    unsigned r = x.u + 0x7fffu + ((x.u >> 16) & 1u);
    return (ushort_t)(r >> 16);
}
__device__ __forceinline__ float bf2f(ushort_t u) {
    union { unsigned u; float f; } x; x.u = ((unsigned)u) << 16; return x.f;
}

__device__ __forceinline__ void gload_lds16(const void* g, void* l) {
    __builtin_amdgcn_global_load_lds(
        (const __attribute__((address_space(1))) void*)g,
        (__attribute__((address_space(3))) void*)l, 16, 0, 0);
}

// ---------------------------------------------------------------- embedding
__global__ __launch_bounds__(256) void embed_k(const int* __restrict__ x,
                                               const float* __restrict__ emb,
                                               float* __restrict__ h) {
    int row = blockIdx.x;
    int tok = x[row];
    const float4* src = (const float4*)(emb + (size_t)tok * D_);
    float4* dst = (float4*)(h + (size_t)row * D_);
    dst[threadIdx.x] = src[threadIdx.x];
}

// ---------------------------------------------- residual + split-K reduce
// h += p0 + p1 (fp32). Only used for the last-layer W2 partials (the final
// ln_wt writes wdecT over pbuf's region, so fusing there would race).
__global__ __launch_bounds__(256) void resadd_k(float* __restrict__ h,
                                                const float* __restrict__ p0,
                                                const float* __restrict__ p1) {
    size_t i = (size_t)blockIdx.x * 256 + threadIdx.x;
    float4 a = ((const float4*)h)[i];
    float4 b = ((const float4*)p0)[i];
    float4 c = ((const float4*)p1)[i];
    a.x += b.x + c.x; a.y += b.y + c.y; a.z += b.z + c.z; a.w += b.w + c.w;
    ((float4*)h)[i] = a;
}

// ------------------------------------------------------------ device bodies
// LN (faithful: divide by var + 1e-12, NO sqrt). Optional fused split-K
// reduce: when p0!=null, h[row] += p0[row]+p1[row] first (row-exclusive).
__device__ __forceinline__ void ln_body(int row, float* __restrict__ x,
                                        const float* __restrict__ p0,
                                        const float* __restrict__ p1,
                                        const float* __restrict__ w,
                                        const float* __restrict__ bb,
                                        ushort_t* __restrict__ out16,
                                        ushort_t* __restrict__ out16l,
                                        float* red) {
    float4* xr = (float4*)(x + (size_t)row * D_);
    float4 v = xr[threadIdx.x];
    if (p0) {
        float4 b = ((const float4*)(p0 + (size_t)row * D_))[threadIdx.x];
        float4 c = ((const float4*)(p1 + (size_t)row * D_))[threadIdx.x];
        v.x += b.x + c.x; v.y += b.y + c.y; v.z += b.z + c.z; v.w += b.w + c.w;
        xr[threadIdx.x] = v;
    }
    float s = v.x + v.y + v.z + v.w;
    #pragma unroll
    for (int off = 32; off; off >>= 1) s += __shfl_xor(s, off);
    int wave = threadIdx.x >> 6, lane = threadIdx.x & 63;
    if (lane == 0) red[wave] = s;
    __syncthreads();
    float m = (red[0] + red[1] + red[2] + red[3]) * (1.f / 1024.f);
    float dx = v.x - m, dy = v.y - m, dz = v.z - m, dw = v.w - m;
    float ss = dx*dx + dy*dy + dz*dz + dw*dw;
    #pragma unroll
    for (int off = 32; off; off >>= 1) ss += __shfl_xor(ss, off);
    __syncthreads();
    if (lane == 0) red[wave] = ss;
    __syncthreads();
    float var = (red[0] + red[1] + red[2] + red[3]) * (1.f / 1024.f);
    float inv = 1.f / (var + 1e-12f);
    float4 wv = ((const float4*)w)[threadIdx.x];
    float4 bv = ((const float4*)bb)[threadIdx.x];
    float4 ov;
    ov.x = wv.x * dx * inv + bv.x;
    ov.y = wv.y * dy * inv + bv.y;
    ov.z = wv.z * dz * inv + bv.z;
    ov.w = wv.w * dw * inv + bv.w;
    ushort4 oh;
    oh.x = f2bf(ov.x); oh.y = f2bf(ov.y); oh.z = f2bf(ov.z); oh.w = f2bf(ov.w);
    ((ushort4*)(out16 + (size_t)row * D_))[threadIdx.x] = oh;
    if (out16l) {
        ushort4 ol;
        ol.x = f2bf(ov.x - bf2f(oh.x));
        ol.y = f2bf(ov.y - bf2f(oh.y));
        ol.z = f2bf(ov.z - bf2f(oh.z));
        ol.w = f2bf(ov.w - bf2f(oh.w));
        ((ushort4*)(out16l + (size_t)row * D_))[threadIdx.x] = ol;
    }
}

// weight transpose fp32->bf16 (optional lo residual output)
__device__ __forceinline__ void wt_body(int tile, const float* __restrict__ W,
                                        ushort_t* __restrict__ Wt,
                                        ushort_t* __restrict__ Wtl,
                                        int K, int N, float (*t)[33]) {
    int nT = N >> 5;
    int n0 = (tile % nT) << 5, k0 = (tile / nT) << 5;
    int r = threadIdx.x >> 3, c4 = (threadIdx.x & 7) << 2;
    float4 v = *(const float4*)(W + (size_t)(k0 + r) * N + n0 + c4);
    t[r][c4+0] = v.x; t[r][c4+1] = v.y; t[r][c4+2] = v.z; t[r][c4+3] = v.w;
    __syncthreads();
    float v0 = t[c4+0][r], v1 = t[c4+1][r], v2 = t[c4+2][r], v3 = t[c4+3][r];
    ushort4 oh;
    oh.x = f2bf(v0); oh.y = f2bf(v1); oh.z = f2bf(v2); oh.w = f2bf(v3);
    size_t off = (size_t)(n0 + r) * K + k0 + c4;
    *(ushort4*)(Wt + off) = oh;
    if (Wtl) {
        ushort4 ol;
        ol.x = f2bf(v0 - bf2f(oh.x));
        ol.y = f2bf(v1 - bf2f(oh.y));
        ol.z = f2bf(v2 - bf2f(oh.z));
        ol.w = f2bf(v3 - bf2f(oh.w));
        *(ushort4*)(Wtl + off) = ol;
    }
}

// v [bh][s][64] -> vT [bh][d][s]
__device__ __forceinline__ void vt_body(int blk, const ushort_t* __restrict__ vb,
                                        ushort_t* __restrict__ vtb,
                                        ushort_t (*t)[72]) {
    int st = blk & 15, bh = blk >> 4;
    int tid = threadIdx.x;
    int sr = tid >> 2, c0 = (tid & 3) * 16;
    const ushort_t* src = vb + ((size_t)bh*S_ + st*64 + sr) * 64 + c0;
    *(uint4*)&t[sr][c0]     = *(const uint4*)src;
    *(uint4*)&t[sr][c0 + 8] = *(const uint4*)(src + 8);
    __syncthreads();
    int d = tid >> 2, s0 = (tid & 3) * 16;
    ushort_t vo[16];
    #pragma unroll
    for (int u = 0; u < 16; ++u) vo[u] = t[s0+u][d];
    size_t vout = ((size_t)bh*64 + d) * S_ + st*64 + s0;
    *(uint4*)(vtb + vout)     = *(uint4*)&vo[0];
    *(uint4*)(vtb + vout + 8) = *(uint4*)&vo[8];
}

// ------------------------------------------- fused: LN(+reduce) + up to two wt's
__global__ __launch_bounds__(256) void ln_wt_k(
    float* __restrict__ x,
    const float* __restrict__ p0, const float* __restrict__ p1,
    const float* __restrict__ lnw, const float* __restrict__ lnb,
    ushort_t* __restrict__ out16, ushort_t* __restrict__ out16l,
    const float* __restrict__ Wa, ushort_t* __restrict__ WaT,
    ushort_t* __restrict__ WaTl, int Ka, int Na,
    const float* __restrict__ Wb, ushort_t* __restrict__ WbT, int Kb, int Nb)
{
    __shared__ __align__(16) char sh[4352];
    int bid = blockIdx.x;
    if (bid < M_) {
        ln_body(bid, x, p0, p1, lnw, lnb, out16, out16l, (float*)sh);
    } else {
        bid -= M_;
        int tilesA = (Ka >> 5) * (Na >> 5);
        if (bid < tilesA) {
            wt_body(bid, Wa, WaT, WaTl, Ka, Na, (float(*)[33])sh);
        } else {
            wt_body(bid - tilesA, Wb, WbT, nullptr, Kb, Nb, (float(*)[33])sh);
        }
    }
}

// ------------------------------------------- fused: vt + wt(Wo)
__global__ __launch_bounds__(256) void vt_wt_k(
    const ushort_t* __restrict__ vb, ushort_t* __restrict__ vtb,
    const float* __restrict__ W, ushort_t* __restrict__ Wt, int K, int N)
{
    __shared__ __align__(16) char sh[9216];
    int bid = blockIdx.x;
    if (bid < B_*H_*(S_/64)) {
        vt_body(bid, vb, vtb, (ushort_t(*)[72])sh);
    } else {
        wt_body(bid - B_*H_*(S_/64), W, Wt, nullptr, K, N, (float(*)[33])sh);
    }
}

// ------------------------------------------- bf16 MFMA flash attn (layers>=1)
__global__ __launch_bounds__(256) void attn_mfma_k(const ushort_t* __restrict__ qb,
                                                   const ushort_t* __restrict__ kb,
                                                   const ushort_t* __restrict__ vtb,
                                                   ushort_t* __restrict__ o) {
    __shared__ __align__(16) char Kl[16384];   // [128 key][128B]
    __shared__ __align__(16) char Vl[16384];   // [64 d][256B]
    __shared__ __align__(16) char Pl[16384];   // 4 waves x [16 q][256B]
    int blk = blockIdx.x;
    int qt = 15 - (blk & 15);            // longest first
    int bh = blk >> 4;
    int hh = bh & 15, bb = bh >> 4;
    int tid = threadIdx.x, w = tid >> 6, lane = tid & 63;
    int lg = lane >> 4, lr = lane & 15;

    const ushort_t* qhb = qb + ((size_t)bh*S_ + qt*64 + w*16 + lr) * 64;
    bf16x8_t aq0 = *(const bf16x8_t*)(qhb + lg*8);
    bf16x8_t aq1 = *(const bf16x8_t*)(qhb + 32 + lg*8);

    f32x4_t oacc[4];
    #pragma unroll
    for (int n = 0; n < 4; ++n) oacc[n] = (f32x4_t){0.f,0.f,0.f,0.f};
    float m[4] = {-3.0e38f,-3.0e38f,-3.0e38f,-3.0e38f};
    float l[4] = {0.f,0.f,0.f,0.f};

    int kr = tid >> 1;
    int kboff = (tid & 1) * 64;
    int vd = tid >> 2;
    int vboff = (tid & 3) * 64;
    const ushort_t* kg = kb  + (size_t)bh * S_ * 64;
    const ushort_t* vg = vtb + (size_t)bh * 64 * S_;

    int ktl = qt >> 1;
    for (int kt = 0; kt <= ktl; ++kt) {
        __syncthreads();
        {
            const ushort_t* src = kg + (size_t)(kt*128 + kr) * 64 + kboff/2;
            uint4 a0 = *(const uint4*)(src);
            uint4 a1 = *(const uint4*)(src + 8);
            uint4 a2 = *(const uint4*)(src + 16);
            uint4 a3 = *(const uint4*)(src + 24);
            int kbase = kr*128 + kboff;
            int kswz = (kr & 7) << 4;
            *(uint4*)(Kl + ((kbase +  0) ^ kswz)) = a0;
            *(uint4*)(Kl + ((kbase + 16) ^ kswz)) = a1;
            *(uint4*)(Kl + ((kbase + 32) ^ kswz)) = a2;
            *(uint4*)(Kl + ((kbase + 48) ^ kswz)) = a3;
            const ushort_t* vs = vg + (size_t)vd * S_ + kt*128 + vboff/2;
            uint4 b0 = *(const uint4*)(vs);
            uint4 b1 = *(const uint4*)(vs + 8);
            uint4 b2 = *(const uint4*)(vs + 16);
            uint4 b3 = *(const uint4*)(vs + 24);
            int vbase = vd*256 + vboff;
            int vswz = (vd & 7) << 4;
            *(uint4*)(Vl + ((vbase +  0) ^ vswz)) = b0;
            *(uint4*)(Vl + ((vbase + 16) ^ vswz)) = b1;
            *(uint4*)(Vl + ((vbase + 32) ^ vswz)) = b2;
            *(uint4*)(Vl + ((vbase + 48) ^ vswz)) = b3;
        }
        __syncthreads();

        f32x4_t sfr[8];
        #pragma unroll
        for (int n = 0; n < 8; ++n) sfr[n] = (f32x4_t){0.f,0.f,0.f,0.f};
        __builtin_amdgcn_s_setprio(1);
        #pragma unroll
        for (int n = 0; n < 8; ++n) {
            int row = n*16 + lr;
            int swz = (row & 7) << 4;
            bf16x8_t b0 = *(const bf16x8_t*)(Kl + ((row*128 + lg*16) ^ swz));
            bf16x8_t b1 = *(const bf16x8_t*)(Kl + ((row*128 + 64 + lg*16) ^ swz));
            sfr[n] = __builtin_amdgcn_mfma_f32_16x16x32_bf16(aq0, b0, sfr[n], 0,0,0);
            sfr[n] = __builtin_amdgcn_mfma_f32_16x16x32_bf16(aq1, b1, sfr[n], 0,0,0);
        }
        __builtin_amdgcn_s_setprio(0);

        if (kt == ktl) {
            #pragma unroll
            for (int n = 0; n < 8; ++n) {
                int key = kt*128 + n*16 + lr;
                #pragma unroll
                for (int j = 0; j < 4; ++j) {
                    int qrow = qt*64 + w*16 + lg*4 + j;
                    if (key > qrow) sfr[n][j] = -3.0e38f;
                }
            }
        }

        float sc[4];
        #pragma unroll
        for (int j = 0; j < 4; ++j) {
            float v = sfr[0][j];
            #pragma unroll
            for (int n = 1; n < 8; ++n) v = fmaxf(v, sfr[n][j]);
            v = fmaxf(v, __shfl_xor(v, 1));
            v = fmaxf(v, __shfl_xor(v, 2));
            v = fmaxf(v, __shfl_xor(v, 4));
            v = fmaxf(v, __shfl_xor(v, 8));
            float mn = fmaxf(m[j], v);
            sc[j] = __expf(m[j] - mn);
            m[j] = mn;
        }
        #pragma unroll
        for (int n = 0; n < 8; ++n)
            #pragma unroll
            for (int j = 0; j < 4; ++j)
                sfr[n][j] = __expf(sfr[n][j] - m[j]);
        #pragma unroll
        for (int j = 0; j < 4; ++j) {
            float s = sfr[0][j];
            #pragma unroll
            for (int n = 1; n < 8; ++n) s += sfr[n][j];
            s += __shfl_xor(s, 1);
            s += __shfl_xor(s, 2);
            s += __shfl_xor(s, 4);
            s += __shfl_xor(s, 8);
            l[j] = l[j] * sc[j] + s;
            #pragma unroll
            for (int n = 0; n < 4; ++n) oacc[n][j] *= sc[j];
        }

        #pragma unroll
        for (int n = 0; n < 8; ++n) {
            #pragma unroll
            for (int j = 0; j < 4; ++j) {
                int row = lg*4 + j;
                int byt = (w*4096 + row*256 + (n*16 + lr)*2) ^ ((row & 7) << 4);
                *(ushort_t*)(Pl + byt) = f2bf(sfr[n][j]);
            }
        }
        int pswz = (lr & 7) << 4;
        bf16x8_t pa0 = *(const bf16x8_t*)(Pl + ((w*4096 + lr*256 +   0 + lg*16) ^ pswz));
        bf16x8_t pa1 = *(const bf16x8_t*)(Pl + ((w*4096 + lr*256 +  64 + lg*16) ^ pswz));
        bf16x8_t pa2 = *(const bf16x8_t*)(Pl + ((w*4096 + lr*256 + 128 + lg*16) ^ pswz));
        bf16x8_t pa3 = *(const bf16x8_t*)(Pl + ((w*4096 + lr*256 + 192 + lg*16) ^ pswz));

        __builtin_amdgcn_s_setprio(1);
        #pragma unroll
        for (int n = 0; n < 4; ++n) {
            int row = n*16 + lr;
            int swz = (row & 7) << 4;
            bf16x8_t v0 = *(const bf16x8_t*)(Vl + ((row*256 +   0 + lg*16) ^ swz));
            bf16x8_t v1 = *(const bf16x8_t*)(Vl + ((row*256 +  64 + lg*16) ^ swz));
            bf16x8_t v2 = *(const bf16x8_t*)(Vl + ((row*256 + 128 + lg*16) ^ swz));
            bf16x8_t v3 = *(const bf16x8_t*)(Vl + ((row*256 + 192 + lg*16) ^ swz));
            oacc[n] = __builtin_amdgcn_mfma_f32_16x16x32_bf16(pa0, v0, oacc[n], 0,0,0);
            oacc[n] = __builtin_amdgcn_mfma_f32_16x16x32_bf16(pa1, v1, oacc[n], 0,0,0);
            oacc[n] = __builtin_amdgcn_mfma_f32_16x16x32_bf16(pa2, v2, oacc[n], 0,0,0);
            oacc[n] = __builtin_amdgcn_mfma_f32_16x16x32_bf16(pa3, v3, oacc[n], 0,0,0);
        }
        __builtin_amdgcn_s_setprio(0);
    }

    #pragma unroll
    for (int j = 0; j < 4; ++j) {
        float rl = 1.f / l[j];
        int row = qt*64 + w*16 + lg*4 + j;
        size_t base = (size_t)(bb*S_ + row) * D_ + hh*64;
        #pragma unroll
        for (int n = 0; n < 4; ++n)
            o[base + n*16 + lr] = f2bf(oacc[n][j] * rl);
    }
}

// ------------------------------------------- split-precision MFMA attn, layer 0
__global__ __launch_bounds__(256) void attn_mfma0_k(const ushort_t* __restrict__ qhp,
                                                    const ushort_t* __restrict__ qlp,
                                                    const ushort_t* __restrict__ khp,
                                                    const ushort_t* __restrict__ klp,
                                                    const ushort_t* __restrict__ vtb,
                                                    ushort_t* __restrict__ o) {
    __shared__ __align__(16) char Khl[8192];
    __shared__ __align__(16) char Kll[8192];
    __shared__ __align__(16) char Vl[8192];
    __shared__ __align__(16) char Pl[8192];
    int blk = blockIdx.x;
    int qt = 15 - (blk & 15);
    int bh = blk >> 4;
    int hh = bh & 15, bb = bh >> 4;
    int tid = threadIdx.x, w = tid >> 6, lane = tid & 63;
    int lg = lane >> 4, lr = lane & 15;

    size_t qoff = ((size_t)bh*S_ + qt*64 + w*16 + lr) * 64;
    bf16x8_t aqh0 = *(const bf16x8_t*)(qhp + qoff + lg*8);
    bf16x8_t aqh1 = *(const bf16x8_t*)(qhp + qoff + 32 + lg*8);
    bf16x8_t aql0 = *(const bf16x8_t*)(qlp + qoff + lg*8);
    bf16x8_t aql1 = *(const bf16x8_t*)(qlp + qoff + 32 + lg*8);

    f32x4_t oacc[4];
    #pragma unroll
    for (int n = 0; n < 4; ++n) oacc[n] = (f32x4_t){0.f,0.f,0.f,0.f};
    float m[4] = {-3.0e38f,-3.0e38f,-3.0e38f,-3.0e38f};
    float l[4] = {0.f,0.f,0.f,0.f};

    int srow = tid >> 2;
    int soff = (tid & 3) * 32;
    const ushort_t* kgh = khp + (size_t)bh * S_ * 64;
    const ushort_t* kgl = klp + (size_t)bh * S_ * 64;
    const ushort_t* vg  = vtb + (size_t)bh * 64 * S_;

    for (int kt = 0; kt <= qt; ++kt) {
        __syncthreads();
        {
            int b0 = (srow*128 + soff) ^ ((srow & 7) << 4);
            int b1 = (srow*128 + soff + 16) ^ ((srow & 7) << 4);
            const ushort_t* src = kgh + (size_t)(kt*64 + srow) * 64 + soff/2;
            *(uint4*)(Khl + b0) = *(const uint4*)src;
            *(uint4*)(Khl + b1) = *(const uint4*)(src + 8);
            const ushort_t* srl = kgl + (size_t)(kt*64 + srow) * 64 + soff/2;
            *(uint4*)(Kll + b0) = *(const uint4*)srl;
            *(uint4*)(Kll + b1) = *(const uint4*)(srl + 8);
            const ushort_t* vs = vg + (size_t)srow * S_ + kt*64 + soff/2;
            *(uint4*)(Vl + b0) = *(const uint4*)vs;
            *(uint4*)(Vl + b1) = *(const uint4*)(vs + 8);
        }
        __syncthreads();

        f32x4_t sfr[4];
        #pragma unroll
        for (int n = 0; n < 4; ++n) sfr[n] = (f32x4_t){0.f,0.f,0.f,0.f};
        __builtin_amdgcn_s_setprio(1);
        #pragma unroll
        for (int n = 0; n < 4; ++n) {
            int row = n*16 + lr;
            int swz = (row & 7) << 4;
            bf16x8_t bh0 = *(const bf16x8_t*)(Khl + ((row*128 + lg*16) ^ swz));
            bf16x8_t bh1 = *(const bf16x8_t*)(Khl + ((row*128 + 64 + lg*16) ^ swz));
            bf16x8_t bl0 = *(const bf16x8_t*)(Kll + ((row*128 + lg*16) ^ swz));
            bf16x8_t bl1 = *(const bf16x8_t*)(Kll + ((row*128 + 64 + lg*16) ^ swz));
            sfr[n] = __builtin_amdgcn_mfma_f32_16x16x32_bf16(aqh0, bh0, sfr[n], 0,0,0);
            sfr[n] = __builtin_amdgcn_mfma_f32_16x16x32_bf16(aqh1, bh1, sfr[n], 0,0,0);
            sfr[n] = __builtin_amdgcn_mfma_f32_16x16x32_bf16(aqh0, bl0, sfr[n], 0,0,0);
            sfr[n] = __builtin_amdgcn_mfma_f32_16x16x32_bf16(aqh1, bl1, sfr[n], 0,0,0);
            sfr[n] = __builtin_amdgcn_mfma_f32_16x16x32_bf16(aql0, bh0, sfr[n], 0,0,0);
            sfr[n] = __builtin_amdgcn_mfma_f32_16x16x32_bf16(aql1, bh1, sfr[n], 0,0,0);
        }
        __builtin_amdgcn_s_setprio(0);

        if (kt == qt) {
            #pragma unroll
            for (int n = 0; n < 4; ++n) {
                int key = n*16 + lr;
                #pragma unroll
                for (int j = 0; j < 4; ++j) {
                    int qrow = w*16 + lg*4 + j;
                    if (key > qrow) sfr[n][j] = -3.0e38f;
                }
            }
        }

        float sc[4];
        #pragma unroll
        for (int j = 0; j < 4; ++j) {
            float v = fmaxf(fmaxf(sfr[0][j], sfr[1][j]), fmaxf(sfr[2][j], sfr[3][j]));
            v = fmaxf(v, __shfl_xor(v, 1));
            v = fmaxf(v, __shfl_xor(v, 2));
            v = fmaxf(v, __shfl_xor(v, 4));
            v = fmaxf(v, __shfl_xor(v, 8));
            float mn = fmaxf(m[j], v);
            sc[j] = __expf(m[j] - mn);
            m[j] = mn;
        }
        #pragma unroll
        for (int n = 0; n < 4; ++n)
            #pragma unroll
            for (int j = 0; j < 4; ++j)
                sfr[n][j] = __expf(sfr[n][j] - m[j]);
        #pragma unroll
        for (int j = 0; j < 4; ++j) {
            float s = sfr[0][j] + sfr[1][j] + sfr[2][j] + sfr[3][j];
            s += __shfl_xor(s, 1);
            s += __shfl_xor(s, 2);
            s += __shfl_xor(s, 4);
            s += __shfl_xor(s, 8);
            l[j] = l[j] * sc[j] + s;
            #pragma unroll
            for (int n = 0; n < 4; ++n) oacc[n][j] *= sc[j];
        }

        #pragma unroll
        for (int n = 0; n < 4; ++n) {
            #pragma unroll
            for (int j = 0; j < 4; ++j) {
                int row = lg*4 + j;
                int byt = (w*2048 + row*128 + (n*16 + lr)*2) ^ ((row & 7) << 4);
                *(ushort_t*)(Pl + byt) = f2bf(sfr[n][j]);
            }
        }
        int pswz = (lr & 7) << 4;
        bf16x8_t pa0 = *(const bf16x8_t*)(Pl + ((w*2048 + lr*128 + lg*16) ^ pswz));
        bf16x8_t pa1 = *(const bf16x8_t*)(Pl + ((w*2048 + lr*128 + 64 + lg*16) ^ pswz));

        __builtin_amdgcn_s_setprio(1);
        #pragma unroll
        for (int n = 0; n < 4; ++n) {
            int row = n*16 + lr;
            int swz = (row & 7) << 4;
            bf16x8_t v0 = *(const bf16x8_t*)(Vl + ((row*128 + lg*16) ^ swz));
            bf16x8_t v1 = *(const bf16x8_t*)(Vl + ((row*128 + 64 + lg*16) ^ swz));
            oacc[n] = __builtin_amdgcn_mfma_f32_16x16x32_bf16(pa0, v0, oacc[n], 0,0,0);
            oacc[n] = __builtin_amdgcn_mfma_f32_16x16x32_bf16(pa1, v1, oacc[n], 0,0,0);
        }
        __builtin_amdgcn_s_setprio(0);
    }

    #pragma unroll
    for (int j = 0; j < 4; ++j) {
        float rl = 1.f / l[j];
        int row = qt*64 + w*16 + lg*4 + j;
        size_t base = (size_t)(bb*S_ + row) * D_ + hh*64;
        #pragma unroll
        for (int n = 0; n < 4; ++n)
            o[base + n*16 + lr] = f2bf(oacc[n][j] * rl);
    }
}

// ---------------------------------------------------------------- GEMM bf16
__device__ __forceinline__ float gelu_f(float x) {
    return 0.5f * x * (1.f + erff(x * 0.70710678118654752f));
}

// 128x128 tile, 4 waves (2x2). T2 XOR-swizzled LDS; transpose epilogue.
// epi: 0 = fp32 out, 1 = fp32 + Res, 2 = gelu->bf16
template<int TM>
__global__ __launch_bounds__(2*TM, 4) void gemm_bf16_k(
    const ushort_t* __restrict__ A,
    const ushort_t* __restrict__ Bt,
    const float* __restrict__ Res,
    float* __restrict__ Cf,
    ushort_t* __restrict__ Cb,
    int M, int N, int K, int epi)
{
    __shared__ __align__(16) char smem[TM*128 + 128*128];  // As | Bs (bytes)
    ushort_t* As = (ushort_t*)smem;
    ushort_t* Bs = (ushort_t*)(smem + TM*128);
    int tid = threadIdx.x;
    int wid = tid >> 6, lane = tid & 63;
    int wm = wid >> 1;
    int wn = wid & 1;
    int bm = blockIdx.x * TM, bn = blockIdx.y * 128;

    f32x4_t acc[4][4];
    #pragma unroll
    for (int m = 0; m < 4; ++m)
        #pragma unroll
        for (int n = 0; n < 4; ++n)
            acc[m][n] = (f32x4_t){0.f, 0.f, 0.f, 0.f};

    int srow = (lane >> 3);
    int scol = (((lane & 7) ^ (lane >> 3)) * 8);   // pre-swizzled source chunk

    for (int k0 = 0; k0 < K; k0 += 64) {
        __syncthreads();
        #pragma unroll
        for (int i = 0; i < 4; ++i) {
            int rb = i * (TM/4) + wid * 8;
            gload_lds16(A + (size_t)(bm + rb + srow) * K + k0 + scol, &As[rb * 64]);
        }
        #pragma unroll
        for (int i = 0; i < 4; ++i) {
            int rb = i * 32 + wid * 8;
            gload_lds16(Bt + (size_t)(bn + rb + srow) * K + k0 + scol, &Bs[rb * 64]);
        }
        __syncthreads();
        #pragma unroll
        for (int kk = 0; kk < 64; kk += 32) {
            bf16x8_t af[4], bfr[4];
            int kof = kk + (lane >> 4) * 8;
            #pragma unroll
            for (int m = 0; m < 4; ++m) {
                int r = wm * 64 + m * 16 + (lane & 15);
                af[m] = *(const bf16x8_t*)&As[(r * 64 + kof) ^ ((r & 7) << 3)];
            }
            #pragma unroll
            for (int n = 0; n < 4; ++n) {
                int r = wn * 64 + n * 16 + (lane & 15);
                bfr[n] = *(const bf16x8_t*)&Bs[(r * 64 + kof) ^ ((r & 7) << 3)];
            }
            #pragma unroll
            for (int m = 0; m < 4; ++m)
                #pragma unroll
                for (int n = 0; n < 4; ++n)
                    acc[m][n] = __builtin_amdgcn_mfma_f32_16x16x32_bf16(
                        af[m], bfr[n], acc[m][n], 0, 0, 0);
        }
    }

    // ---- epilogue: LDS fragment transpose, full-line stores ----
    __syncthreads();
    float* scr = (float*)smem + (size_t)wid * 1088;   // 16 rows x 68 (padded)
    int cr = (lane >> 4) * 4, cc = lane & 15;
    #pragma unroll
    for (int m = 0; m < 4; ++m) {
        #pragma unroll
        for (int n = 0; n < 4; ++n)
            #pragma unroll
            for (int j = 0; j < 4; ++j)
                scr[(cr + j) * 68 + n * 16 + cc] = acc[m][n][j];
        #pragma unroll
        for (int i = 0; i < 4; ++i) {
            int rr = i * 4 + (lane >> 4);
            int c2 = (lane & 15) * 4;
            float4 v = *(float4*)&scr[rr * 68 + c2];
            int row = bm + wm * 64 + m * 16 + rr;
            int col = bn + wn * 64 + c2;
            size_t off = (size_t)row * N + col;
            if (epi == 0) {
                *(float4*)&Cf[off] = v;
            } else if (epi == 1) {
                float4 r4 = *(const float4*)&Res[off];
                v.x += r4.x; v.y += r4.y; v.z += r4.z; v.w += r4.w;
                *(float4*)&Cf[off] = v;
            } else {
                ushort4 o4;
                o4.x = f2bf(gelu_f(v.x)); o4.y = f2bf(gelu_f(v.y));
                o4.z = f2bf(gelu_f(v.z)); o4.w = f2bf(gelu_f(v.w));
                *(ushort4*)&Cb[off] = o4;
            }
        }
    }
}

// 256x128 tile, 4 waves each 64x128 (acc[4][8]) -- decode GEMM.
// 1-D grid + XCD swizzle (T1); NT full-line C stores.
__global__ __launch_bounds__(256, 2) void gemm256_k(
    const ushort_t* __restrict__ A,
    const ushort_t* __restrict__ Bt,
    float* __restrict__ Cf,
    int M, int N, int K)
{
    __shared__ __align__(16) char smem[256*128 + 128*128];  // As 32KB | Bs 16KB
    ushort_t* As = (ushort_t*)smem;
    ushort_t* Bs = (ushort_t*)(smem + 256*128);
    int tid = threadIdx.x;
    int wid = tid >> 6, lane = tid & 63;
    int bid = blockIdx.x;
    int nPerXcd = (M >> 8) * (N >> 7) / 8;          // 2000/8 = 250
    int wg = (bid & 7) * nPerXcd + (bid >> 3);
    int bm = (wg & 7) * 256;
    int bn = (wg >> 3) * 128;

    f32x4_t acc[4][8];
    #pragma unroll
    for (int m = 0; m < 4; ++m)
        #pragma unroll
        for (int n = 0; n < 8; ++n)
            acc[m][n] = (f32x4_t){0.f, 0.f, 0.f, 0.f};

    int srow = (lane >> 3);
    int scol = (((lane & 7) ^ (lane >> 3)) * 8);

    for (int k0 = 0; k0 < K; k0 += 64) {
        __syncthreads();
        #pragma unroll
        for (int i = 0; i < 8; ++i) {
            int rb = i * 32 + wid * 8;
            gload_lds16(A + (size_t)(bm + rb + srow) * K + k0 + scol, &As[rb * 64]);
        }
        #pragma unroll
        for (int i = 0; i < 4; ++i) {
            int rb = i * 32 + wid * 8;
            gload_lds16(Bt + (size_t)(bn + rb + srow) * K + k0 + scol, &Bs[rb * 64]);
        }
        __syncthreads();
        #pragma unroll
        for (int kk = 0; kk < 64; kk += 32) {
            bf16x8_t af[4], bfr[8];
            int kof = kk + (lane >> 4) * 8;
            #pragma unroll
            for (int m = 0; m < 4; ++m) {
                int r = wid * 64 + m * 16 + (lane & 15);
                af[m] = *(const bf16x8_t*)&As[(r * 64 + kof) ^ ((r & 7) << 3)];
            }
            #pragma unroll
            for (int n = 0; n < 8; ++n) {
                int r = n * 16 + (lane & 15);
                bfr[n] = *(const bf16x8_t*)&Bs[(r * 64 + kof) ^ ((r & 7) << 3)];
            }
            #pragma unroll
            for (int m = 0; m < 4; ++m)
                #pragma unroll
                for (int n = 0; n < 8; ++n)
                    acc[m][n] = __builtin_amdgcn_mfma_f32_16x16x32_bf16(
                        af[m], bfr[n], acc[m][n], 0, 0, 0);
        }
    }

    // epilogue: per-wave 16x68 scratch, two 64-col halves; NT full-line stores
    __syncthreads();
    float* scr = (float*)smem + (size_t)wid * 1088;
    int cr = (lane >> 4) * 4, cc = lane & 15;
    #pragma unroll
    for (int m = 0; m < 4; ++m) {
        #pragma unroll
        for (int half = 0; half < 2; ++half) {
            #pragma unroll
            for (int n = 0; n < 4; ++n)
                #pragma unroll
                for (int j = 0; j < 4; ++j)
                    scr[(cr + j) * 68 + n * 16 + cc] = acc[m][half*4 + n][j];
            #pragma unroll
            for (int i = 0; i < 4; ++i) {
                int rr = i * 4 + (lane >> 4);
                int c2 = (lane & 15) * 4;
                f32x4_t v = *(f32x4_t*)&scr[rr * 68 + c2];
                int row = bm + wid * 64 + m * 16 + rr;
                int col = bn + half * 64 + c2;
                __builtin_nontemporal_store(v, (f32x4_t*)&Cf[(size_t)row * N + col]);
            }
        }
    }
}

// 64x128 tile, 4 waves each 64x32 (acc[4][2]) -- small-grid Wo/W2 GEMMs.
// Split-K=2 via gridDim.z: each z computes K/2 inner slice, writes fp32
// partial at Cf + z*M*N (epi=0). 2 blocks/CU covers the barrier-drain
// stall; deeper split regresses (r26: partial traffic > occupancy gain).
__global__ __launch_bounds__(256, 4) void gemm64_k(
    const ushort_t* __restrict__ A,
    const ushort_t* __restrict__ Bt,
    const float* __restrict__ Res,
    float* __restrict__ Cf,
    ushort_t* __restrict__ Cb,
    int M, int N, int K, int epi)
{
    __shared__ __align__(16) char smem[64*128 + 128*128];  // As 8KB | Bs 16KB
    ushort_t* As = (ushort_t*)smem;
    ushort_t* Bs = (ushort_t*)(smem + 64*128);
    int tid = threadIdx.x;
    int wid = tid >> 6, lane = tid & 63;
    int bm = blockIdx.x * 64, bn = blockIdx.y * 128;
    int z = blockIdx.z;
    int kPer = K / (int)gridDim.z;
    int kEnd = (z + 1) * kPer;

    f32x4_t acc[4][2];
    #pragma unroll
    for (int m = 0; m < 4; ++m)
        #pragma unroll
        for (int n = 0; n < 2; ++n)
            acc[m][n] = (f32x4_t){0.f, 0.f, 0.f, 0.f};

    int srow = (lane >> 3);
    int scol = (((lane & 7) ^ (lane >> 3)) * 8);

    for (int k0 = z * kPer; k0 < kEnd; k0 += 64) {
        __syncthreads();
        #pragma unroll
        for (int i = 0; i < 2; ++i) {
            int rb = i * 32 + wid * 8;
            gload_lds16(A + (size_t)(bm + rb + srow) * K + k0 + scol, &As[rb * 64]);
        }
        #pragma unroll
        for (int i = 0; i < 4; ++i) {
            int rb = i * 32 + wid * 8;
            gload_lds16(Bt + (size_t)(bn + rb + srow) * K + k0 + scol, &Bs[rb * 64]);
        }
        __syncthreads();
        #pragma unroll
        for (int kk = 0; kk < 64; kk += 32) {
            bf16x8_t af[4], bfr[2];
            int kof = kk + (lane >> 4) * 8;
            #pragma unroll
            for (int m = 0; m < 4; ++m) {
                int r = m * 16 + (lane & 15);
                af[m] = *(const bf16x8_t*)&As[(r * 64 + kof) ^ ((r & 7) << 3)];
            }
            #pragma unroll
            for (int n = 0; n < 2; ++n) {
                int r = wid * 32 + n * 16 + (lane & 15);
                bfr[n] = *(const bf16x8_t*)&Bs[(r * 64 + kof) ^ ((r & 7) << 3)];
            }
            #pragma unroll
            for (int m = 0; m < 4; ++m)
                #pragma unroll
                for (int n = 0; n < 2; ++n)
                    acc[m][n] = __builtin_amdgcn_mfma_f32_16x16x32_bf16(
                        af[m], bfr[n], acc[m][n], 0, 0, 0);
        }
    }

    // epilogue: per-wave 16x36 fp32 scratch, float4/ushort4 stores
    __syncthreads();
    float* scr = (float*)smem + (size_t)wid * 576;
    int cr = (lane >> 4) * 4, cc = lane & 15;
    size_t zoff = (size_t)z * M * N;
    #pragma unroll
    for (int m = 0; m < 4; ++m) {
        #pragma unroll
        for (int n = 0; n < 2; ++n)
            #pragma unroll
            for (int j = 0; j < 4; ++j)
                scr[(cr + j) * 36 + n * 16 + cc] = acc[m][n][j];
        #pragma unroll
        for (int i = 0; i < 2; ++i) {
            int rr = i * 8 + (lane >> 3);          // 0..15
            int c2 = (lane & 7) * 4;               // 0..28
            float4 v = *(float4*)&scr[rr * 36 + c2];
            int row = bm + m * 16 + rr;
            int col = bn + wid * 32 + c2;
            size_t off = (size_t)row * N + col;
            if (epi == 0) {
                *(float4*)&Cf[zoff + off] = v;
            } else if (epi == 1) {
                float4 r4 = *(const float4*)&Res[off];
                v.x += r4.x; v.y += r4.y; v.z += r4.z; v.w += r4.w;
                *(float4*)&Cf[off] = v;
            } else {
                ushort4 o4;
                o4.x = f2bf(gelu_f(v.x)); o4.y = f2bf(gelu_f(v.y));
                o4.z = f2bf(gelu_f(v.z)); o4.w = f2bf(gelu_f(v.w));
                *(ushort4*)&Cb[off] = o4;
            }
        }
    }
}

// ----------------------- QKV GEMM with fused RoPE + bf16 epilogue (layers>=1)
__global__ __launch_bounds__(256, 4) void gemm_qkv_k(
    const ushort_t* __restrict__ A,
    const ushort_t* __restrict__ Bt,
    ushort_t* __restrict__ qb, ushort_t* __restrict__ kb,
    ushort_t* __restrict__ vb)
{
    __shared__ __align__(16) ushort_t As[128 * 64];
    __shared__ __align__(16) ushort_t Bs[128 * 64];
    const int K = D_;
    int tid = threadIdx.x;
    int wid = tid >> 6, lane = tid & 63;
    int wm = wid >> 1, wn = wid & 1;
    int bm = blockIdx.x * 128, bn = blockIdx.y * 128;

    f32x4_t acc[4][4];
    #pragma unroll
    for (int m = 0; m < 4; ++m)
        #pragma unroll
        for (int n = 0; n < 4; ++n)
            acc[m][n] = (f32x4_t){0.f, 0.f, 0.f, 0.f};

    int srow = (lane >> 3);
    int scol = (((lane & 7) ^ (lane >> 3)) * 8);

    for (int k0 = 0; k0 < K; k0 += 64) {
        __syncthreads();
        #pragma unroll
        for (int i = 0; i < 4; ++i) {
            int rb = i * 32 + wid * 8;
            gload_lds16(A  + (size_t)(bm + rb + srow) * K + k0 + scol, &As[rb * 64]);
            gload_lds16(Bt + (size_t)(bn + rb + srow) * K + k0 + scol, &Bs[rb * 64]);
        }
        __syncthreads();
        #pragma unroll
        for (int kk = 0; kk < 64; kk += 32) {
            bf16x8_t af[4], bfr[4];
            int kof = kk + (lane >> 4) * 8;
            #pragma unroll
            for (int m = 0; m < 4; ++m) {
                int r = wm * 64 + m * 16 + (lane & 15);
                af[m] = *(const bf16x8_t*)&As[(r * 64 + kof) ^ ((r & 7) << 3)];
            }
            #pragma unroll
            for (int n = 0; n < 4; ++n) {
                int r = wn * 64 + n * 16 + (lane & 15);
                bfr[n] = *(const bf16x8_t*)&Bs[(r * 64 + kof) ^ ((r & 7) << 3)];
            }
            #pragma unroll
            for (int m = 0; m < 4; ++m)
                #pragma unroll
                for (int n = 0; n < 4; ++n)
                    acc[m][n] = __builtin_amdgcn_mfma_f32_16x16x32_bf16(
                        af[m], bfr[n], acc[m][n], 0, 0, 0);
        }
    }

    int cr = (lane >> 4) * 4, cc = lane & 15;
    float csn[4], snn[4];
    int partn[4], headn[4], dn[4];
    #pragma unroll
    for (int n = 0; n < 4; ++n) {
        int col = bn + wn*64 + n*16 + cc;
        int head = col / 192;
        int rem = col - head*192;
        partn[n] = rem >> 6;
        dn[n] = rem & 63;
        headn[n] = head;
        float inv = exp2f((float)(dn[n] >> 1) * (-13.287712379549449f / 32.f));
        sincosf((float)head * inv, &snn[n], &csn[n]);
    }
    bool odd = (lane & 1);
    #pragma unroll
    for (int m = 0; m < 4; ++m) {
        int row = bm + wm * 64 + m * 16 + cr;
        #pragma unroll
        for (int n = 0; n < 4; ++n) {
            ushort_t* dst = (partn[n] == 0) ? qb : (partn[n] == 1) ? kb : vb;
            #pragma unroll
            for (int j = 0; j < 4; ++j) {
                float a = acc[m][n][j];
                float p = __shfl_xor(a, 1);
                float outv;
                if (partn[n] == 2) outv = a;
                else {
                    outv = odd ? (p*snn[n] + a*csn[n]) : (a*csn[n] - p*snn[n]);
                    if (partn[n] == 0) outv *= 0.125f;
                }
                int r = row + j;
                size_t off = ((size_t)((r >> 10)*16 + headn[n]) * S_ + (r & 1023)) * 64 + dn[n];
                dst[off] = f2bf(outv);
            }
        }
    }
}

// -------------- layer-0: split-precision QKV GEMM + fused rope/split epilogue
__global__ __launch_bounds__(256, 2) void gemm_split_qkv_k(
    const ushort_t* __restrict__ Ah, const ushort_t* __restrict__ Al,
    const ushort_t* __restrict__ Bh, const ushort_t* __restrict__ Bl,
    ushort_t* __restrict__ qhb, ushort_t* __restrict__ qlb,
    ushort_t* __restrict__ khb, ushort_t* __restrict__ klb,
    ushort_t* __restrict__ vb)
{
    __shared__ __align__(16) ushort_t Ash[128 * 64];
    __shared__ __align__(16) ushort_t Asl[128 * 64];
    __shared__ __align__(16) ushort_t Bsh[128 * 64];
    __shared__ __align__(16) ushort_t Bsl[128 * 64];
    const int K = D_;
    int tid = threadIdx.x;
    int wid = tid >> 6, lane = tid & 63;
    int wm = wid >> 1, wn = wid & 1;
    int bm = blockIdx.x * 128, bn = blockIdx.y * 128;

    f32x4_t acc[4][4];
    #pragma unroll
    for (int m = 0; m < 4; ++m)
        #pragma unroll
        for (int n = 0; n < 4; ++n)
            acc[m][n] = (f32x4_t){0.f, 0.f, 0.f, 0.f};

    int srow = (lane >> 3);
    int scol = (((lane & 7) ^ (lane >> 3)) * 8);

    for (int k0 = 0; k0 < K; k0 += 64) {
        __syncthreads();
        #pragma unroll
        for (int i = 0; i < 4; ++i) {
            int rb = i * 32 + wid * 8;
            size_t ga = (size_t)(bm + rb + srow) * K + k0 + scol;
            size_t gb = (size_t)(bn + rb + srow) * K + k0 + scol;
            gload_lds16(Ah + ga, &Ash[rb * 64]);
            gload_lds16(Al + ga, &Asl[rb * 64]);
            gload_lds16(Bh + gb, &Bsh[rb * 64]);
            gload_lds16(Bl + gb, &Bsl[rb * 64]);
        }
        __syncthreads();
        #pragma unroll
        for (int kk = 0; kk < 64; kk += 32) {
            bf16x8_t ah[4], al[4], bhf[4], blf[4];
            int kof = kk + (lane >> 4) * 8;
            #pragma unroll
            for (int m = 0; m < 4; ++m) {
                int r = wm * 64 + m * 16 + (lane & 15);
                int ro = (r * 64 + kof) ^ ((r & 7) << 3);
                ah[m] = *(const bf16x8_t*)&Ash[ro];
                al[m] = *(const bf16x8_t*)&Asl[ro];
            }
            #pragma unroll
            for (int n = 0; n < 4; ++n) {
                int r = wn * 64 + n * 16 + (lane & 15);
                int ro = (r * 64 + kof) ^ ((r & 7) << 3);
                bhf[n] = *(const bf16x8_t*)&Bsh[ro];
                blf[n] = *(const bf16x8_t*)&Bsl[ro];
            }
            #pragma unroll
            for (int m = 0; m < 4; ++m)
                #pragma unroll
                for (int n = 0; n < 4; ++n) {
                    acc[m][n] = __builtin_amdgcn_mfma_f32_16x16x32_bf16(
                        ah[m], bhf[n], acc[m][n], 0, 0, 0);
                    acc[m][n] = __builtin_amdgcn_mfma_f32_16x16x32_bf16(
                        ah[m], blf[n], acc[m][n], 0, 0, 0);
                    acc[m][n] = __builtin_amdgcn_mfma_f32_16x16x32_bf16(
                        al[m], bhf[n], acc[m][n], 0, 0, 0);
                }
        }
    }

    int cr = (lane >> 4) * 4, cc = lane & 15;
    float csn[4], snn[4];
    int partn[4], headn[4], dn[4];
    #pragma unroll
    for (int n = 0; n < 4; ++n) {
        int col = bn + wn*64 + n*16 + cc;
        int head = col / 192;
        int rem = col - head*192;
        partn[n] = rem >> 6;
        dn[n] = rem & 63;
        headn[n] = head;
        float inv = exp2f((float)(dn[n] >> 1) * (-13.287712379549449f / 32.f));
        sincosf((float)head * inv, &snn[n], &csn[n]);
    }
    bool odd = (lane & 1);
    #pragma unroll
    for (int m = 0; m < 4; ++m) {
        int row = bm + wm * 64 + m * 16 + cr;
        #pragma unroll
        for (int n = 0; n < 4; ++n) {
            #pragma unroll
            for (int j = 0; j < 4; ++j) {
                float a = acc[m][n][j];
                float p = __shfl_xor(a, 1);
                int r = row + j;
                size_t off = ((size_t)((r >> 10)*16 + headn[n]) * S_ + (r & 1023)) * 64 + dn[n];
                if (partn[n] == 2) {
                    vb[off] = f2bf(a);
                } else {
                    float outv = odd ? (p*snn[n] + a*csn[n]) : (a*csn[n] - p*snn[n]);
                    if (partn[n] == 0) outv *= 0.125f;
                    ushort_t hi = f2bf(outv);
                    ushort_t lo = f2bf(outv - bf2f(hi));
                    if (partn[n] == 0) { qhb[off] = hi; qlb[off] = lo; }
                    else               { khb[off] = hi; klb[off] = lo; }
                }
            }
        }
    }
}

// ---------------------------------------------------------------- launch
extern "C" void kernel_launch(void* const* d_in, const int* in_sizes, int n_in,
                              void* d_out, int out_size, void* d_ws, size_t ws_size,
                              hipStream_t stream) {
    const int*   x    = (const int*)  d_in[0];
    const float* emb  = (const float*)d_in[1];
    const float* ln1w = (const float*)d_in[2];
    const float* ln1b = (const float*)d_in[3];
    const float* Wqkv = (const float*)d_in[4];
    const float* Wo   = (const float*)d_in[5];
    const float* ln2w = (const float*)d_in[6];
    const float* ln2b = (const float*)d_in[7];
    const float* W1   = (const float*)d_in[8];
    const float* W2   = (const float*)d_in[9];
    const float* lnfw = (const float*)d_in[10];
    const float* lnfb = (const float*)d_in[11];
    const float* Wdec = (const float*)d_in[12];
    float* out = (float*)d_out;

    // ---- workspace layout (bytes), lifetime-aliased, 80 MB total ----
    char* ws = (char*)d_ws;
    float*    h     = (float*)   (ws + 0);              // 8 MB  [2048,1024] f32
    ushort_t* xnb   = (ushort_t*)(ws + (8u<<20));       // 4 MB  LN out hi
    ushort_t* ob    = (ushort_t*)(ws + (12u<<20));      // 4 MB  attn out / xl (l=0)
    ushort_t* q_bf  = (ushort_t*)(ws + (16u<<20));      // 4 MB  q (qh for l=0)
    ushort_t* k_bf  = (ushort_t*)(ws + (20u<<20));      // 4 MB  k (kh for l=0)
    ushort_t* vT_bf = (ushort_t*)(ws + (24u<<20));      // 4 MB  vT
    ushort_t* v_bf  = (ushort_t*)(ws + (28u<<20));      // 4 MB  v row-major
    ushort_t* ql0   = (ushort_t*)(ws + (32u<<20));      // 4 MB  ql (l=0)
    ushort_t* kl0   = (ushort_t*)(ws + (36u<<20));      // 4 MB  kl (l=0)
    float*    pbuf  = (float*)   (ws + (16u<<20));      // 16 MB split-K partials
                                                        //  (aliases q..v, dead post-attn)
    ushort_t* ffb   = (ushort_t*)(ws + (40u<<20));      // 16 MB [2048,4096] bf16
    ushort_t* wqkvT = (ushort_t*)(ws + (56u<<20));      // 6 MB  [3072,1024] bf16
    ushort_t* woT   = (ushort_t*)(ws + (62u<<20));      // 2 MB  [1024,1024] bf16
    ushort_t* w1T   = (ushort_t*)(ws + (64u<<20));      // 8 MB  [4096,1024] bf16
    ushort_t* w2T   = (ushort_t*)(ws + (72u<<20));      // 8 MB  [1024,4096] bf16
    ushort_t* wqkvTl= (ushort_t*)(ws + (64u<<20));      // 6 MB  (l=0 only, dead before wt(W1))
    ushort_t* wdecT = (ushort_t*)(ws + (16u<<20));      // 64 MB, aliases q_bf..w2T (post-loop)

    const int tQKV = (D_/32)*(3*D_/32);     // 3072
    const int tWo  = (D_/32)*(D_/32);       // 1024
    const int tW1  = (D_/32)*(DFF_/32);     // 4096
    const int tW2  = (DFF_/32)*(D_/32);     // 4096
    const int tDec = (D_/32)*(V_/32);       // 32000
    const int nVt  = B_*H_*(S_/64);         // 512
    float* pb1 = pbuf + (size_t)M_*D_;

    embed_k<<<M_, 256, 0, stream>>>(x, emb, h);
    for (int l = 0; l < L_; ++l) {
        // W2 partials of layer l-1 fuse into this ln1 (null for l==0)
        const float* rp0 = (l == 0) ? nullptr : pbuf;
        const float* rp1 = (l == 0) ? nullptr : pb1;
        if (l == 0) {
            ln_wt_k<<<M_ + tQKV, 256, 0, stream>>>(
                h, rp0, rp1, ln1w, ln1b, xnb, ob /*=xl*/,
                Wqkv, wqkvT, wqkvTl, D_, 3*D_, nullptr, nullptr, 0, 0);
            gemm_split_qkv_k<<<dim3(M_/128, 3*D_/128), 256, 0, stream>>>(
                xnb, ob /*=xl*/, wqkvT, wqkvTl, q_bf, ql0, k_bf, kl0, v_bf);
            vt_wt_k<<<nVt + tWo, 256, 0, stream>>>(
                v_bf, vT_bf, Wo + (size_t)l*D_*D_, woT, D_, D_);
            attn_mfma0_k<<<nVt, 256, 0, stream>>>(
                q_bf, ql0, k_bf, kl0, vT_bf, ob);
        } else {
            ln_wt_k<<<M_ + tQKV, 256, 0, stream>>>(
                h, rp0, rp1, ln1w + l*D_, ln1b + l*D_, xnb, nullptr,
                Wqkv + (size_t)l*D_*3*D_, wqkvT, nullptr, D_, 3*D_,
                nullptr, nullptr, 0, 0);
            gemm_qkv_k<<<dim3(M_/128, 3*D_/128), 256, 0, stream>>>(
                xnb, wqkvT, q_bf, k_bf, v_bf);
            vt_wt_k<<<nVt + tWo, 256, 0, stream>>>(
                v_bf, vT_bf, Wo + (size_t)l*D_*D_, woT, D_, D_);
            attn_mfma_k<<<nVt, 256, 0, stream>>>(q_bf, k_bf, vT_bf, ob);
        }
        // Wo GEMM: split-K=2 partials (q..v dead); reduce fused into ln2
        gemm64_k<<<dim3(M_/64, D_/128, 2), 256, 0, stream>>>(
            ob, woT, nullptr, pbuf, nullptr, M_, D_, D_, 0);
        ln_wt_k<<<M_ + tW1 + tW2, 256, 0, stream>>>(
            h, pbuf, pb1, ln2w + l*D_, ln2b + l*D_, xnb, nullptr,
            W1 + (size_t)l*D_*DFF_, w1T, nullptr, D_, DFF_,
            W2 + (size_t)l*DFF_*D_, w2T, DFF_, D_);
        gemm_bf16_k<128><<<dim3(M_/128, DFF_/128), 256, 0, stream>>>(
            xnb, w1T, nullptr, nullptr, ffb, M_, DFF_, D_, 2);
        gemm64_k<<<dim3(M_/64, D_/128, 2), 256, 0, stream>>>(
            ffb, w2T, nullptr, pbuf, nullptr, M_, D_, DFF_, 0);
        // reduce fuses into next layer's ln1 (or resadd before final LN)
    }
    // last W2 reduce must precede final ln_wt (wdecT overwrites pbuf region)
    resadd_k<<<M_*D_/1024, 256, 0, stream>>>(h, pbuf, pb1);
    ln_wt_k<<<M_ + tDec, 256, 0, stream>>>(
        h, nullptr, nullptr, lnfw, lnfb, xnb, nullptr,
        Wdec, wdecT, nullptr, D_, V_, nullptr, nullptr, 0, 0);
    gemm256_k<<<(M_/256)*(V_/128), 256, 0, stream>>>(
        xnb, wdecT, out, M_, V_, D_);
}